// Round 1
// baseline (89302.252 us; speedup 1.0000x reference)
//
#include <hip/hip_runtime.h>
#include <cmath>

// ---------------------------------------------------------------------------
// Graves handwriting-synthesis model: 3-layer GRU + attention window + MDN head
// B=32 T=512 U=64 V=60 H=400 K=10 M=20 IN=3
//
// Strategy (round 1, correctness-first):
//  - Sequential scans as persistent-grid kernels (100 blocks x 256 thr), hidden
//    units sliced 4/WG, all gate weights (input-side + recurrent) in LDS once.
//  - Hand-rolled device-scope grid barrier between steps (100 blocks always
//    co-resident on 256 CUs; agent-scope atomics + __threadfence for x-XCD).
//  - Layer0: 2 barriers/step (h-phase, attention-phase). L1/L2: 1 barrier/step.
//  - Head GEMM + log_softmax/exp/tanh postprocess fused, writes all 6 outputs.
// ---------------------------------------------------------------------------

namespace {
constexpr int B_ = 32, T_ = 512, U_ = 64, V_ = 60, H_ = 400, K_ = 10, M_ = 20;

// workspace layout (in floats)
constexpr size_t SZ_OUT   = (size_t)B_ * T_ * H_;          // 6,553,600
constexpr size_t OFF_OUT0 = 0;
constexpr size_t OFF_OUT1 = OFF_OUT0 + SZ_OUT;
constexpr size_t OFF_OUT2 = OFF_OUT1 + SZ_OUT;
constexpr size_t OFF_WSEQ = OFF_OUT2 + SZ_OUT;             // B*T*V = 983,040
constexpr size_t OFF_H    = OFF_WSEQ + (size_t)B_ * T_ * V_;
constexpr size_t OFF_BAR  = OFF_H + 2 * (size_t)B_ * H_;   // 2 uints
// total ~20.7M floats = ~83 MB

// d_out layout (floats), concatenated in reference return order
constexpr int DO_MEANS = 0;                     // (B,T,M,2)
constexpr int DO_STD   = B_ * T_ * M_ * 2;      // 655360
constexpr int DO_LOGW  = DO_STD + B_ * T_ * M_; // 983040
constexpr int DO_CORR  = DO_LOGW + B_ * T_ * M_;// 1310720
constexpr int DO_LAST  = DO_CORR + B_ * T_ * M_;// 1638400
constexpr int DO_PHI   = DO_LAST + B_ * T_;     // 1654784  (B,1,U+1)
} // namespace

// ---------------------------------------------------------------------------

__device__ __forceinline__ float f4dot(const float* __restrict__ w,
                                       const float* __restrict__ g, int n4) {
  const float4* w4 = reinterpret_cast<const float4*>(w);
  const float4* g4 = reinterpret_cast<const float4*>(g);
  float acc = 0.f;
#pragma unroll 4
  for (int i = 0; i < n4; ++i) {
    float4 a = w4[i];
    float4 b = g4[i];
    acc = fmaf(a.x, b.x, acc);
    acc = fmaf(a.y, b.y, acc);
    acc = fmaf(a.z, b.z, acc);
    acc = fmaf(a.w, b.w, acc);
  }
  return acc;
}

__device__ __forceinline__ float sigmoidf_(float x) {
  return 1.f / (1.f + __expf(-x));
}

// sense-free generation barrier: cnt + gen, device scope.
__device__ __forceinline__ void grid_barrier(unsigned* cnt, unsigned* gen,
                                             unsigned nblk) {
  __threadfence();   // release my global writes to agent scope
  __syncthreads();
  if (threadIdx.x == 0) {
    unsigned g = __hip_atomic_load(gen, __ATOMIC_RELAXED, __HIP_MEMORY_SCOPE_AGENT);
    unsigned a = __hip_atomic_fetch_add(cnt, 1u, __ATOMIC_ACQ_REL, __HIP_MEMORY_SCOPE_AGENT);
    if (a == nblk - 1u) {
      __hip_atomic_store(cnt, 0u, __ATOMIC_RELAXED, __HIP_MEMORY_SCOPE_AGENT);
      __hip_atomic_store(gen, g + 1u, __ATOMIC_RELEASE, __HIP_MEMORY_SCOPE_AGENT);
    } else {
      while (__hip_atomic_load(gen, __ATOMIC_ACQUIRE, __HIP_MEMORY_SCOPE_AGENT) == g) {
        __builtin_amdgcn_s_sleep(2);
      }
    }
  }
  __syncthreads();
  __threadfence();   // acquire: don't read stale lines after the barrier
}

// ---------------------------------------------------------------------------
// init: zero h ping-pong buffers + barrier state
__global__ void init_kernel(float* __restrict__ hbuf, unsigned* __restrict__ bar) {
  int i = blockIdx.x * blockDim.x + threadIdx.x;
  if (i < 2 * B_ * H_) hbuf[i] = 0.f;
  if (i < 2) bar[i] = 0u;
}

// ---------------------------------------------------------------------------
// scan kernel. LAYER=0: input = [x(3) | w(60)], runs attention phase.
// LAYER=1/2: input = [x(3) | out_prev(400) | wseq(60)].
// Grid: 100 blocks x 256 threads. Block wg owns hidden units wg*4 .. wg*4+3.
//
// LDS weight row layouts (per unit), all segments 16B aligned:
//   r/z rows : [x0 x1 x2 pad | (L0: w 60) (L1/2: outprev 400, wseq 60) | h 400]
//   inn rows : same minus the h segment
//   hn rows  : [h 400]
template <int LAYER>
__global__ __launch_bounds__(256)
void scan_kernel(const float* __restrict__ x, const int* __restrict__ c,
                 const float* __restrict__ Wih, const float* __restrict__ Whh,
                 const float* __restrict__ bih, const float* __restrict__ bhh,
                 const float* __restrict__ Ww, const float* __restrict__ bw,
                 const float* __restrict__ inprev,  // out_{l-1} (L1/2)
                 float* __restrict__ outbuf,        // out_l  (B*T*H)
                 float* __restrict__ wseq,          // B*T*V
                 float* __restrict__ hbuf,          // 2*B*H ping-pong
                 float* __restrict__ out_phi,       // d_out + DO_PHI (L0)
                 unsigned* __restrict__ bar) {
  constexpr int I   = (LAYER == 0) ? 63 : 463;   // input-concat width
  constexpr int SRZ = (LAYER == 0) ? 464 : 864;  // r/z row stride (floats)
  constexpr int SI  = (LAYER == 0) ? 64 : 464;   // inn row stride
  constexpr int HOFF = SRZ - H_;                 // h-segment offset in r/z rows

  __shared__ __align__(16) float sWr[4 * SRZ];
  __shared__ __align__(16) float sWz[4 * SRZ];
  __shared__ __align__(16) float sWni[4 * SI];
  __shared__ __align__(16) float sWnh[4 * H_];
  __shared__ float sbr[4], sbz[4], sbni[4], sbnh[4];
  __shared__ float sdots[B_][17];   // 17: break bank aliasing
  // layer-0 attention scratch
  __shared__ __align__(16) float sh[H_];
  __shared__ float spart[30 * 8];
  __shared__ float sp[30];
  __shared__ float sphi[U_ + 1];
  __shared__ float skap[K_];
  __shared__ int sc[U_];

  const int wg = blockIdx.x;   // 0..99
  const int u0 = wg * 4;       // global hidden-unit base

  // ---- load weight slices into LDS (once) ----
  for (int t0 = threadIdx.x; t0 < 4 * SRZ; t0 += 256) {
    int u = t0 / SRZ, o = t0 % SRZ;
    int jr = u0 + u;
    float vr, vz;
    if (o < 3) {
      vr = Wih[jr * I + o];
      vz = Wih[(H_ + jr) * I + o];
    } else if (o == 3) {
      vr = 0.f; vz = 0.f;
    } else if (o < HOFF) {
      int col = o - 1;  // o=4 -> col 3
      vr = Wih[jr * I + col];
      vz = Wih[(H_ + jr) * I + col];
    } else {
      int k = o - HOFF;
      vr = Whh[jr * H_ + k];
      vz = Whh[(H_ + jr) * H_ + k];
    }
    sWr[t0] = vr;
    sWz[t0] = vz;
  }
  for (int t0 = threadIdx.x; t0 < 4 * SI; t0 += 256) {
    int u = t0 / SI, o = t0 % SI;
    int jr = 2 * H_ + u0 + u;  // n-gate input rows
    float v;
    if (o < 3)      v = Wih[jr * I + o];
    else if (o == 3) v = 0.f;
    else             v = Wih[jr * I + (o - 1)];
    sWni[t0] = v;
  }
  for (int t0 = threadIdx.x; t0 < 4 * H_; t0 += 256) {
    int u = t0 / H_, k = t0 % H_;
    sWnh[t0] = Whh[(2 * H_ + u0 + u) * H_ + k];
  }
  if (threadIdx.x < 4) {
    int u = threadIdx.x, jr = u0 + u;
    sbr[u]  = bih[jr] + bhh[jr];
    sbz[u]  = bih[H_ + jr] + bhh[H_ + jr];
    sbni[u] = bih[2 * H_ + jr];
    sbnh[u] = bhh[2 * H_ + jr];
  }
  if constexpr (LAYER == 0) {
    if (wg < B_) {
      for (int i = threadIdx.x; i < U_; i += 256) sc[i] = c[wg * U_ + i];
      if (threadIdx.x < K_) skap[threadIdx.x] = 0.f;
    }
  }
  __syncthreads();

  // ---- time loop ----
  for (int t = 0; t < T_; ++t) {
    const int par = t & 1;
    const float* hprev = hbuf + (size_t)par * B_ * H_;
    float* hnext = hbuf + (size_t)(1 - par) * B_ * H_;

    // phase A: gate dots. 16 dots per batch (4 units x {r,z,inn,hn}).
    {
      const int b = threadIdx.x & 31, slot = threadIdx.x >> 5;
      const int row = b * T_ + t;
      const float x0 = x[row * 3 + 0], x1 = x[row * 3 + 1], x2 = x[row * 3 + 2];
      for (int d = slot; d < 16; d += 8) {
        int u = d >> 2, kind = d & 3;
        float acc;
        if (kind <= 1) {
          const float* Wrow = (kind == 0 ? sWr : sWz) + u * SRZ;
          acc = (kind == 0 ? sbr[u] : sbz[u]);
          acc += Wrow[0] * x0 + Wrow[1] * x1 + Wrow[2] * x2;
          if constexpr (LAYER == 0) {
            if (t > 0) acc += f4dot(Wrow + 4, wseq + (size_t)(row - 1) * V_, V_ / 4);
          } else {
            acc += f4dot(Wrow + 4, inprev + (size_t)row * H_, H_ / 4);
            acc += f4dot(Wrow + 4 + H_, wseq + (size_t)row * V_, V_ / 4);
          }
          acc += f4dot(Wrow + HOFF, hprev + b * H_, H_ / 4);
        } else if (kind == 2) {
          const float* Wrow = sWni + u * SI;
          acc = sbni[u];
          acc += Wrow[0] * x0 + Wrow[1] * x1 + Wrow[2] * x2;
          if constexpr (LAYER == 0) {
            if (t > 0) acc += f4dot(Wrow + 4, wseq + (size_t)(row - 1) * V_, V_ / 4);
          } else {
            acc += f4dot(Wrow + 4, inprev + (size_t)row * H_, H_ / 4);
            acc += f4dot(Wrow + 4 + H_, wseq + (size_t)row * V_, V_ / 4);
          }
        } else {
          acc = sbnh[u] + f4dot(sWnh + u * H_, hprev + b * H_, H_ / 4);
        }
        sdots[b][d] = acc;
      }
    }
    __syncthreads();
    if (threadIdx.x < 128) {
      int b = threadIdx.x & 31, u = threadIdx.x >> 5;
      float r = sigmoidf_(sdots[b][u * 4 + 0]);
      float z = sigmoidf_(sdots[b][u * 4 + 1]);
      float n = tanhf(sdots[b][u * 4 + 2] + r * sdots[b][u * 4 + 3]);
      int j = u0 + u;
      float hp = hprev[b * H_ + j];
      float hv = (1.f - z) * n + z * hp;
      hnext[b * H_ + j] = hv;
      outbuf[(size_t)(b * T_ + t) * H_ + j] = hv;
    }
    grid_barrier(bar, bar + 1, gridDim.x);

    if constexpr (LAYER == 0) {
      // phase B: attention window for batch = blockIdx (blocks 0..31)
      if (wg < B_) {
        const int b = wg;
        for (int i = threadIdx.x; i < H_; i += 256) sh[i] = hnext[b * H_ + i];
        __syncthreads();
        if (threadIdx.x < 240) {
          int m = threadIdx.x >> 3, part = threadIdx.x & 7;
          float acc = 0.f;
          int k0 = part * 50;
          for (int k = k0; k < k0 + 50; ++k) acc = fmaf(sh[k], Ww[m * H_ + k], acc);
          spart[m * 8 + part] = acc;
        }
        __syncthreads();
        if (threadIdx.x < 30) {
          int m = threadIdx.x;
          float s = bw[m];
          for (int i = 0; i < 8; ++i) s += spart[m * 8 + i];
          sp[m] = __expf(s);  // alpha | beta | dkappa after exp
        }
        __syncthreads();
        if (threadIdx.x < K_) skap[threadIdx.x] += sp[20 + threadIdx.x];
        __syncthreads();
        if (threadIdx.x < U_ + 1) {
          float uu = (float)threadIdx.x, s = 0.f;
          for (int k = 0; k < K_; ++k) {
            float diff = skap[k] - uu;
            s = fmaf(sp[k], __expf(-sp[10 + k] * diff * diff), s);
          }
          sphi[threadIdx.x] = s;
        }
        __syncthreads();
        if (threadIdx.x < V_) {
          int v = threadIdx.x;
          float s = 0.f;
          for (int uu = 0; uu < U_; ++uu)
            if (sc[uu] == v) s += sphi[uu];
          wseq[(size_t)(b * T_ + t) * V_ + v] = s;
        }
        if (t == T_ - 1 && threadIdx.x < U_ + 1)
          out_phi[b * (U_ + 1) + threadIdx.x] = sphi[threadIdx.x];
      }
      grid_barrier(bar, bar + 1, gridDim.x);
    }
  }
}

// ---------------------------------------------------------------------------
// head: p = [out0|out1|out2] @ Wh.T + bh (only first 101 of 121 cols used),
// then log_softmax / exp / tanh split into the 5 dense outputs.
__global__ __launch_bounds__(256)
void head_kernel(const float* __restrict__ out0, const float* __restrict__ out1,
                 const float* __restrict__ out2, const float* __restrict__ Wh,
                 const float* __restrict__ bh, float* __restrict__ dout) {
  __shared__ float spd[32 * 101];
  const int rl = threadIdx.x & 31, slot = threadIdx.x >> 5;
  const int row = blockIdx.x * 32 + rl;  // row = b*T + t
  const float* f0 = out0 + (size_t)row * H_;
  const float* f1 = out1 + (size_t)row * H_;
  const float* f2 = out2 + (size_t)row * H_;
  for (int o = slot; o < 101; o += 8) {
    const float* wr = Wh + (size_t)o * 1200;
    float acc = bh[o];
    acc += f4dot(wr, f0, H_ / 4);
    acc += f4dot(wr + H_, f1, H_ / 4);
    acc += f4dot(wr + 2 * H_, f2, H_ / 4);
    spd[rl * 101 + o] = acc;
  }
  __syncthreads();
  if (threadIdx.x < 32) {
    const int r = blockIdx.x * 32 + threadIdx.x;
    const float* p = &spd[threadIdx.x * 101];
    dout[DO_LAST + r] = p[0];
    float mx = -1e30f;
    for (int m = 0; m < M_; ++m) mx = fmaxf(mx, p[1 + m]);
    float s = 0.f;
    for (int m = 0; m < M_; ++m) s += __expf(p[1 + m] - mx);
    float lse = mx + logf(s);
    for (int m = 0; m < M_; ++m) dout[DO_LOGW + r * M_ + m] = p[1 + m] - lse;
    for (int i = 0; i < 2 * M_; ++i) dout[DO_MEANS + r * 2 * M_ + i] = p[1 + M_ + i];
    for (int m = 0; m < M_; ++m) dout[DO_STD + r * M_ + m] = __expf(p[1 + 3 * M_ + m]);
    for (int m = 0; m < M_; ++m) dout[DO_CORR + r * M_ + m] = tanhf(p[1 + 4 * M_ + m]);
  }
}

// ---------------------------------------------------------------------------
extern "C" void kernel_launch(void* const* d_in, const int* in_sizes, int n_in,
                              void* d_out, int out_size, void* d_ws, size_t ws_size,
                              hipStream_t stream) {
  const float* x    = (const float*)d_in[0];
  const int*   c    = (const int*)d_in[1];
  const float* Wih0 = (const float*)d_in[2];
  const float* Whh0 = (const float*)d_in[3];
  const float* bih0 = (const float*)d_in[4];
  const float* bhh0 = (const float*)d_in[5];
  const float* Wih1 = (const float*)d_in[6];
  const float* Whh1 = (const float*)d_in[7];
  const float* bih1 = (const float*)d_in[8];
  const float* bhh1 = (const float*)d_in[9];
  const float* Wih2 = (const float*)d_in[10];
  const float* Whh2 = (const float*)d_in[11];
  const float* bih2 = (const float*)d_in[12];
  const float* bhh2 = (const float*)d_in[13];
  const float* Ww   = (const float*)d_in[14];
  const float* bw   = (const float*)d_in[15];
  const float* Wh   = (const float*)d_in[16];
  const float* bh   = (const float*)d_in[17];
  (void)in_sizes; (void)n_in; (void)out_size; (void)ws_size;

  float* ws = (float*)d_ws;
  float* out0 = ws + OFF_OUT0;
  float* out1 = ws + OFF_OUT1;
  float* out2 = ws + OFF_OUT2;
  float* wseq = ws + OFF_WSEQ;
  float* hbuf = ws + OFF_H;
  unsigned* bar = (unsigned*)(ws + OFF_BAR);
  float* dout = (float*)d_out;

  const dim3 blk(256);
  const dim3 initg(100), scang(100), headg((B_ * T_) / 32);

  init_kernel<<<initg, blk, 0, stream>>>(hbuf, bar);
  scan_kernel<0><<<scang, blk, 0, stream>>>(x, c, Wih0, Whh0, bih0, bhh0, Ww, bw,
                                            nullptr, out0, wseq, hbuf,
                                            dout + DO_PHI, bar);
  init_kernel<<<initg, blk, 0, stream>>>(hbuf, bar);
  scan_kernel<1><<<scang, blk, 0, stream>>>(x, c, Wih1, Whh1, bih1, bhh1, Ww, bw,
                                            out0, out1, wseq, hbuf, nullptr, bar);
  init_kernel<<<initg, blk, 0, stream>>>(hbuf, bar);
  scan_kernel<2><<<scang, blk, 0, stream>>>(x, c, Wih2, Whh2, bih2, bhh2, Ww, bw,
                                            out1, out2, wseq, hbuf, nullptr, bar);
  head_kernel<<<headg, blk, 0, stream>>>(out0, out1, out2, Wh, bh, dout);
}

// Round 2
// 56851.556 us; speedup vs baseline: 1.5708x; 1.5708x over previous
//
#include <hip/hip_runtime.h>
#include <cmath>

// ---------------------------------------------------------------------------
// Graves handwriting-synthesis model: 3-layer GRU + attention window + MDN head
// B=32 T=512 U=64 V=60 H=400 K=10 M=20 IN=3
//
// Round 2: kill the per-step L2 writeback/invalidate.
//  - Cross-block per-step data (h ping-pong, layer0 wseq) moves via agent-scope
//    RELAXED atomics (global sc0 sc1 -> coherence point / L3). No __threadfence
//    anywhere in the step loop, so L1/L2 stay warm for read-only streams.
//  - Grid barrier: relaxed atomics + explicit s_waitcnt(0) drain before arrival.
//  - h copied to LDS once per step (atomic dword loads), dots read LDS.
//  - f4dot: 4 independent accumulators (break the dependent-FMA chain).
// ---------------------------------------------------------------------------

namespace {
constexpr int B_ = 32, T_ = 512, U_ = 64, V_ = 60, H_ = 400, K_ = 10, M_ = 20;
constexpr int HP_ = 404;  // sh_h row stride: 16B-aligned, 4-way bank conflict only
constexpr int WP_ = 68;   // sw row stride: 16B-aligned, 4-way bank conflict only

// workspace layout (in floats)
constexpr size_t SZ_OUT   = (size_t)B_ * T_ * H_;          // 6,553,600
constexpr size_t OFF_OUT0 = 0;
constexpr size_t OFF_OUT1 = OFF_OUT0 + SZ_OUT;
constexpr size_t OFF_OUT2 = OFF_OUT1 + SZ_OUT;
constexpr size_t OFF_WSEQ = OFF_OUT2 + SZ_OUT;             // B*T*V
constexpr size_t OFF_H    = OFF_WSEQ + (size_t)B_ * T_ * V_;
constexpr size_t OFF_BAR  = OFF_H + 2 * (size_t)B_ * H_;   // 2 uints

// d_out layout (floats), concatenated in reference return order
constexpr int DO_MEANS = 0;                     // (B,T,M,2)
constexpr int DO_STD   = B_ * T_ * M_ * 2;
constexpr int DO_LOGW  = DO_STD + B_ * T_ * M_;
constexpr int DO_CORR  = DO_LOGW + B_ * T_ * M_;
constexpr int DO_LAST  = DO_CORR + B_ * T_ * M_;
constexpr int DO_PHI   = DO_LAST + B_ * T_;     // (B,1,U+1)
} // namespace

// ---------------------------------------------------------------------------

__device__ __forceinline__ float load_agent(const float* p) {
  return __hip_atomic_load(p, __ATOMIC_RELAXED, __HIP_MEMORY_SCOPE_AGENT);
}
__device__ __forceinline__ void store_agent(float* p, float v) {
  __hip_atomic_store(p, v, __ATOMIC_RELAXED, __HIP_MEMORY_SCOPE_AGENT);
}

__device__ __forceinline__ float f4dot(const float* __restrict__ w,
                                       const float* __restrict__ g, int n4) {
  const float4* w4 = reinterpret_cast<const float4*>(w);
  const float4* g4 = reinterpret_cast<const float4*>(g);
  float a0 = 0.f, a1 = 0.f, a2 = 0.f, a3 = 0.f;
#pragma unroll 4
  for (int i = 0; i < n4; ++i) {
    float4 a = w4[i];
    float4 b = g4[i];
    a0 = fmaf(a.x, b.x, a0);
    a1 = fmaf(a.y, b.y, a1);
    a2 = fmaf(a.z, b.z, a2);
    a3 = fmaf(a.w, b.w, a3);
  }
  return (a0 + a1) + (a2 + a3);
}

__device__ __forceinline__ float sigmoidf_(float x) {
  return 1.f / (1.f + __expf(-x));
}

// Fence-free grid barrier. Producer ordering: s_waitcnt(0) drains this wave's
// sc1 stores to the coherence point; __syncthreads covers the other waves
// (compiler emits vmcnt(0) before s_barrier). Consumer ordering: the spin
// load feeds the branch, so post-barrier sc1 loads issue after it.
__device__ __forceinline__ void grid_barrier(unsigned* cnt, unsigned* gen,
                                             unsigned nblk) {
  __builtin_amdgcn_s_waitcnt(0);
  __syncthreads();
  __atomic_signal_fence(__ATOMIC_SEQ_CST);
  if (threadIdx.x == 0) {
    unsigned g = __hip_atomic_load(gen, __ATOMIC_RELAXED, __HIP_MEMORY_SCOPE_AGENT);
    unsigned a = __hip_atomic_fetch_add(cnt, 1u, __ATOMIC_RELAXED, __HIP_MEMORY_SCOPE_AGENT);
    if (a == nblk - 1u) {
      __hip_atomic_store(cnt, 0u, __ATOMIC_RELAXED, __HIP_MEMORY_SCOPE_AGENT);
      __hip_atomic_store(gen, g + 1u, __ATOMIC_RELAXED, __HIP_MEMORY_SCOPE_AGENT);
    } else {
      while (__hip_atomic_load(gen, __ATOMIC_RELAXED, __HIP_MEMORY_SCOPE_AGENT) == g) {
        __builtin_amdgcn_s_sleep(1);
      }
    }
  }
  __atomic_signal_fence(__ATOMIC_SEQ_CST);
  __syncthreads();
}

// ---------------------------------------------------------------------------
__global__ void init_kernel(float* __restrict__ hbuf, unsigned* __restrict__ bar) {
  int i = blockIdx.x * blockDim.x + threadIdx.x;
  if (i < 2 * B_ * H_) hbuf[i] = 0.f;
  if (i < 2) bar[i] = 0u;
}

// ---------------------------------------------------------------------------
// scan kernel. LAYER=0: input = [x(3) | w(60)], runs attention phase.
// LAYER=1/2: input = [x(3) | out_prev(400) | wseq(60)].
// Grid: 100 blocks x 256 threads. Block wg owns hidden units wg*4 .. wg*4+3.
template <int LAYER>
__global__ __launch_bounds__(256)
void scan_kernel(const float* __restrict__ x, const int* __restrict__ c,
                 const float* __restrict__ Wih, const float* __restrict__ Whh,
                 const float* __restrict__ bih, const float* __restrict__ bhh,
                 const float* __restrict__ Ww, const float* __restrict__ bw,
                 const float* __restrict__ inprev,  // out_{l-1} (L1/2)
                 float* __restrict__ outbuf,        // out_l  (B*T*H)
                 float* __restrict__ wseq,          // B*T*V
                 float* __restrict__ hbuf,          // 2*B*H ping-pong
                 float* __restrict__ out_phi,       // d_out + DO_PHI (L0)
                 unsigned* __restrict__ bar) {
  constexpr int I   = (LAYER == 0) ? 63 : 463;   // input-concat width
  constexpr int SRZ = (LAYER == 0) ? 464 : 864;  // r/z row stride (floats)
  constexpr int SI  = (LAYER == 0) ? 64 : 464;   // inn row stride
  constexpr int HOFF = SRZ - H_;                 // h-segment offset in r/z rows

  __shared__ __align__(16) float sWr[4 * SRZ];
  __shared__ __align__(16) float sWz[4 * SRZ];
  __shared__ __align__(16) float sWni[4 * SI];
  __shared__ __align__(16) float sWnh[4 * H_];
  __shared__ __align__(16) float sh_h[B_ * HP_];  // h_{t-1} LDS copy
  __shared__ __align__(16) float sw[B_ * WP_];    // w_{t-1} LDS copy (L0)
  __shared__ float sbr[4], sbz[4], sbni[4], sbnh[4];
  __shared__ float sdots[B_][17];
  // layer-0 attention scratch
  __shared__ __align__(16) float sh[H_];
  __shared__ float spart[30 * 8];
  __shared__ float sp[30];
  __shared__ float sphi[U_ + 1];
  __shared__ float skap[K_];
  __shared__ int sc[U_];

  const int wg = blockIdx.x;   // 0..99
  const int u0 = wg * 4;       // global hidden-unit base

  // ---- load weight slices into LDS (once) ----
  for (int t0 = threadIdx.x; t0 < 4 * SRZ; t0 += 256) {
    int u = t0 / SRZ, o = t0 % SRZ;
    int jr = u0 + u;
    float vr, vz;
    if (o < 3) {
      vr = Wih[jr * I + o];
      vz = Wih[(H_ + jr) * I + o];
    } else if (o == 3) {
      vr = 0.f; vz = 0.f;
    } else if (o < HOFF) {
      int col = o - 1;
      vr = Wih[jr * I + col];
      vz = Wih[(H_ + jr) * I + col];
    } else {
      int k = o - HOFF;
      vr = Whh[jr * H_ + k];
      vz = Whh[(H_ + jr) * H_ + k];
    }
    sWr[t0] = vr;
    sWz[t0] = vz;
  }
  for (int t0 = threadIdx.x; t0 < 4 * SI; t0 += 256) {
    int u = t0 / SI, o = t0 % SI;
    int jr = 2 * H_ + u0 + u;
    float v;
    if (o < 3)      v = Wih[jr * I + o];
    else if (o == 3) v = 0.f;
    else             v = Wih[jr * I + (o - 1)];
    sWni[t0] = v;
  }
  for (int t0 = threadIdx.x; t0 < 4 * H_; t0 += 256) {
    int u = t0 / H_, k = t0 % H_;
    sWnh[t0] = Whh[(2 * H_ + u0 + u) * H_ + k];
  }
  if (threadIdx.x < 4) {
    int u = threadIdx.x, jr = u0 + u;
    sbr[u]  = bih[jr] + bhh[jr];
    sbz[u]  = bih[H_ + jr] + bhh[H_ + jr];
    sbni[u] = bih[2 * H_ + jr];
    sbnh[u] = bhh[2 * H_ + jr];
  }
  if constexpr (LAYER == 0) {
    if (wg < B_) {
      for (int i = threadIdx.x; i < U_; i += 256) sc[i] = c[wg * U_ + i];
      if (threadIdx.x < K_) skap[threadIdx.x] = 0.f;
    }
  }
  __syncthreads();

  // ---- time loop ----
  for (int t = 0; t < T_; ++t) {
    const int par = t & 1;
    const float* hprev = hbuf + (size_t)par * B_ * H_;
    float* hnext = hbuf + (size_t)(1 - par) * B_ * H_;

    // stage: copy h_{t-1} (and w_{t-1} for L0) into LDS via coherent loads
    for (int i = threadIdx.x; i < B_ * H_; i += 256) {
      int b = i / H_, k = i - b * H_;
      sh_h[b * HP_ + k] = load_agent(hprev + i);
    }
    if constexpr (LAYER == 0) {
      for (int i = threadIdx.x; i < B_ * V_; i += 256) {
        int b = i / V_, v = i - b * V_;
        sw[b * WP_ + v] =
            (t == 0) ? 0.f
                     : load_agent(wseq + ((size_t)b * T_ + (t - 1)) * V_ + v);
      }
    }
    __syncthreads();

    // phase A: gate dots. 16 dots per batch (4 units x {r,z,inn,hn}).
    {
      const int b = threadIdx.x & 31, slot = threadIdx.x >> 5;
      const int row = b * T_ + t;
      const float x0 = x[row * 3 + 0], x1 = x[row * 3 + 1], x2 = x[row * 3 + 2];
      const float* hrow = sh_h + b * HP_;
      for (int d = slot; d < 16; d += 8) {
        int u = d >> 2, kind = d & 3;
        float acc;
        if (kind <= 1) {
          const float* Wrow = (kind == 0 ? sWr : sWz) + u * SRZ;
          acc = (kind == 0 ? sbr[u] : sbz[u]);
          acc += Wrow[0] * x0 + Wrow[1] * x1 + Wrow[2] * x2;
          if constexpr (LAYER == 0) {
            acc += f4dot(Wrow + 4, sw + b * WP_, V_ / 4);
          } else {
            acc += f4dot(Wrow + 4, inprev + (size_t)row * H_, H_ / 4);
            acc += f4dot(Wrow + 4 + H_, wseq + (size_t)row * V_, V_ / 4);
          }
          acc += f4dot(Wrow + HOFF, hrow, H_ / 4);
        } else if (kind == 2) {
          const float* Wrow = sWni + u * SI;
          acc = sbni[u];
          acc += Wrow[0] * x0 + Wrow[1] * x1 + Wrow[2] * x2;
          if constexpr (LAYER == 0) {
            acc += f4dot(Wrow + 4, sw + b * WP_, V_ / 4);
          } else {
            acc += f4dot(Wrow + 4, inprev + (size_t)row * H_, H_ / 4);
            acc += f4dot(Wrow + 4 + H_, wseq + (size_t)row * V_, V_ / 4);
          }
        } else {
          acc = sbnh[u] + f4dot(sWnh + u * H_, hrow, H_ / 4);
        }
        sdots[b][d] = acc;
      }
    }
    __syncthreads();
    if (threadIdx.x < 128) {
      int b = threadIdx.x & 31, u = threadIdx.x >> 5;
      float r = sigmoidf_(sdots[b][u * 4 + 0]);
      float z = sigmoidf_(sdots[b][u * 4 + 1]);
      float n = tanhf(sdots[b][u * 4 + 2] + r * sdots[b][u * 4 + 3]);
      int j = u0 + u;
      float hp = sh_h[b * HP_ + j];
      float hv = (1.f - z) * n + z * hp;
      store_agent(hnext + b * H_ + j, hv);          // coherent exchange
      outbuf[(size_t)(b * T_ + t) * H_ + j] = hv;   // plain (kernel-boundary)
    }
    grid_barrier(bar, bar + 1, gridDim.x);

    if constexpr (LAYER == 0) {
      // phase B: attention window, block b in [0,32)
      if (wg < B_) {
        const int b = wg;
        for (int i = threadIdx.x; i < H_; i += 256)
          sh[i] = load_agent(hnext + b * H_ + i);
        __syncthreads();
        if (threadIdx.x < 240) {
          int m = threadIdx.x >> 3, part = threadIdx.x & 7;
          float acc = 0.f;
          int k0 = part * 50;
          for (int k = k0; k < k0 + 50; ++k) acc = fmaf(sh[k], Ww[m * H_ + k], acc);
          spart[m * 8 + part] = acc;
        }
        __syncthreads();
        if (threadIdx.x < 30) {
          int m = threadIdx.x;
          float s = bw[m];
          for (int i = 0; i < 8; ++i) s += spart[m * 8 + i];
          sp[m] = __expf(s);
        }
        __syncthreads();
        if (threadIdx.x < K_) skap[threadIdx.x] += sp[20 + threadIdx.x];
        __syncthreads();
        if (threadIdx.x < U_ + 1) {
          float uu = (float)threadIdx.x, s = 0.f;
          for (int k = 0; k < K_; ++k) {
            float diff = skap[k] - uu;
            s = fmaf(sp[k], __expf(-sp[10 + k] * diff * diff), s);
          }
          sphi[threadIdx.x] = s;
        }
        __syncthreads();
        if (threadIdx.x < V_) {
          int v = threadIdx.x;
          float s = 0.f;
          for (int uu = 0; uu < U_; ++uu)
            if (sc[uu] == v) s += sphi[uu];
          store_agent(wseq + ((size_t)b * T_ + t) * V_ + v, s);
        }
        if (t == T_ - 1 && threadIdx.x < U_ + 1)
          out_phi[b * (U_ + 1) + threadIdx.x] = sphi[threadIdx.x];
      }
      grid_barrier(bar, bar + 1, gridDim.x);
    }
  }
}

// ---------------------------------------------------------------------------
__global__ __launch_bounds__(256)
void head_kernel(const float* __restrict__ out0, const float* __restrict__ out1,
                 const float* __restrict__ out2, const float* __restrict__ Wh,
                 const float* __restrict__ bh, float* __restrict__ dout) {
  __shared__ float spd[32 * 101];
  const int rl = threadIdx.x & 31, slot = threadIdx.x >> 5;
  const int row = blockIdx.x * 32 + rl;  // row = b*T + t
  const float* f0 = out0 + (size_t)row * H_;
  const float* f1 = out1 + (size_t)row * H_;
  const float* f2 = out2 + (size_t)row * H_;
  for (int o = slot; o < 101; o += 8) {
    const float* wr = Wh + (size_t)o * 1200;
    float acc = bh[o];
    acc += f4dot(wr, f0, H_ / 4);
    acc += f4dot(wr + H_, f1, H_ / 4);
    acc += f4dot(wr + 2 * H_, f2, H_ / 4);
    spd[rl * 101 + o] = acc;
  }
  __syncthreads();
  if (threadIdx.x < 32) {
    const int r = blockIdx.x * 32 + threadIdx.x;
    const float* p = &spd[threadIdx.x * 101];
    dout[DO_LAST + r] = p[0];
    float mx = -1e30f;
    for (int m = 0; m < M_; ++m) mx = fmaxf(mx, p[1 + m]);
    float s = 0.f;
    for (int m = 0; m < M_; ++m) s += __expf(p[1 + m] - mx);
    float lse = mx + logf(s);
    for (int m = 0; m < M_; ++m) dout[DO_LOGW + r * M_ + m] = p[1 + m] - lse;
    for (int i = 0; i < 2 * M_; ++i) dout[DO_MEANS + r * 2 * M_ + i] = p[1 + M_ + i];
    for (int m = 0; m < M_; ++m) dout[DO_STD + r * M_ + m] = __expf(p[1 + 3 * M_ + m]);
    for (int m = 0; m < M_; ++m) dout[DO_CORR + r * M_ + m] = tanhf(p[1 + 4 * M_ + m]);
  }
}

// ---------------------------------------------------------------------------
extern "C" void kernel_launch(void* const* d_in, const int* in_sizes, int n_in,
                              void* d_out, int out_size, void* d_ws, size_t ws_size,
                              hipStream_t stream) {
  const float* x    = (const float*)d_in[0];
  const int*   c    = (const int*)d_in[1];
  const float* Wih0 = (const float*)d_in[2];
  const float* Whh0 = (const float*)d_in[3];
  const float* bih0 = (const float*)d_in[4];
  const float* bhh0 = (const float*)d_in[5];
  const float* Wih1 = (const float*)d_in[6];
  const float* Whh1 = (const float*)d_in[7];
  const float* bih1 = (const float*)d_in[8];
  const float* bhh1 = (const float*)d_in[9];
  const float* Wih2 = (const float*)d_in[10];
  const float* Whh2 = (const float*)d_in[11];
  const float* bih2 = (const float*)d_in[12];
  const float* bhh2 = (const float*)d_in[13];
  const float* Ww   = (const float*)d_in[14];
  const float* bw   = (const float*)d_in[15];
  const float* Wh   = (const float*)d_in[16];
  const float* bh   = (const float*)d_in[17];
  (void)in_sizes; (void)n_in; (void)out_size; (void)ws_size;

  float* ws = (float*)d_ws;
  float* out0 = ws + OFF_OUT0;
  float* out1 = ws + OFF_OUT1;
  float* out2 = ws + OFF_OUT2;
  float* wseq = ws + OFF_WSEQ;
  float* hbuf = ws + OFF_H;
  unsigned* bar = (unsigned*)(ws + OFF_BAR);
  float* dout = (float*)d_out;

  const dim3 blk(256);
  const dim3 initg(100), scang(100), headg((B_ * T_) / 32);

  init_kernel<<<initg, blk, 0, stream>>>(hbuf, bar);
  scan_kernel<0><<<scang, blk, 0, stream>>>(x, c, Wih0, Whh0, bih0, bhh0, Ww, bw,
                                            nullptr, out0, wseq, hbuf,
                                            dout + DO_PHI, bar);
  init_kernel<<<initg, blk, 0, stream>>>(hbuf, bar);
  scan_kernel<1><<<scang, blk, 0, stream>>>(x, c, Wih1, Whh1, bih1, bhh1, Ww, bw,
                                            out0, out1, wseq, hbuf, nullptr, bar);
  init_kernel<<<initg, blk, 0, stream>>>(hbuf, bar);
  scan_kernel<2><<<scang, blk, 0, stream>>>(x, c, Wih2, Whh2, bih2, bhh2, Ww, bw,
                                            out1, out2, wseq, hbuf, nullptr, bar);
  head_kernel<<<headg, blk, 0, stream>>>(out0, out1, out2, Wh, bh, dout);
}

// Round 5
// 32874.161 us; speedup vs baseline: 2.7165x; 1.7294x over previous
//
#include <hip/hip_runtime.h>
#include <cmath>

// ---------------------------------------------------------------------------
// Graves handwriting synthesis: 3-layer GRU + attention window + MDN head
// B=32 T=512 U=64 V=60 H=400 K=10 M=20 IN=3
//
// Round 5: round-4 structure + n-gate fix.
//  BUG in r3/r4: layer-0's attention-window input columns were folded into the
//  n-gate recurrent MFMA rows, so they got multiplied by the reset gate r.
//  Reference: n = tanh(inn + r*hn) — input side is OUTSIDE r.
//  FIX: MFMA A-rows 8..11 = Whh_n only; spare rows 12..15 = Wih_n w-part only.
//  sdots[b][12+u] is then added to gn outside the r product. Zero extra cost.
//  Split-bf16 (hi/lo, 3-term MFMA) kept everywhere for fp32-level accuracy.
// ---------------------------------------------------------------------------

typedef __attribute__((ext_vector_type(8))) short bf16x8;
typedef __attribute__((ext_vector_type(4))) float f32x4;
typedef unsigned short ushort_t;

namespace {
constexpr int B_ = 32, T_ = 512, U_ = 64, V_ = 60, H_ = 400, K_ = 10, M_ = 20;
constexpr int N_ = B_ * T_;          // 16384 samples
constexpr int GI_LD = N_;            // gi row stride (fp32)
constexpr int SEG = 416;             // padded per-layer feat segment (13 ktiles)
constexpr int FEAT_LD = 3 * SEG;     // 1248
constexpr int INPX_LD = 64;          // [x(3)|wseq(60)|pad] (2 ktiles)

// workspace layout (float indices)
constexpr size_t OFF_GI    = 0;                                    // 1200*N f32
constexpr size_t OFF_WSEQ  = OFF_GI + (size_t)1200 * N_;           // N*60 f32
constexpr size_t OFF_H     = OFF_WSEQ + (size_t)N_ * V_;           // 2*B*H f32
constexpr size_t OFF_BAR   = OFF_H + 2 * (size_t)B_ * H_;          // 16 f32
constexpr size_t OFF_FEATH = OFF_BAR + 16;                         // N*1248 bf16
constexpr size_t OFF_FEATL = OFF_FEATH + (size_t)N_ * FEAT_LD / 2;
constexpr size_t OFF_INPXH = OFF_FEATL + (size_t)N_ * FEAT_LD / 2; // N*64 bf16
constexpr size_t OFF_INPXL = OFF_INPXH + (size_t)N_ * INPX_LD / 2;
constexpr size_t OFF_WXH   = OFF_INPXL + (size_t)N_ * INPX_LD / 2; // 1200*64 bf16
constexpr size_t OFF_WXL   = OFF_WXH + (size_t)1200 * INPX_LD / 2;
constexpr size_t OFF_WOH   = OFF_WXL + (size_t)1200 * INPX_LD / 2; // 1200*416 bf16
constexpr size_t OFF_WOL   = OFF_WOH + (size_t)1200 * SEG / 2;
constexpr size_t OFF_WHH   = OFF_WOL + (size_t)1200 * SEG / 2;     // 128*1248 bf16
constexpr size_t OFF_WHL   = OFF_WHH + (size_t)128 * FEAT_LD / 2;
// end ~ 42.9M floats ~ 172 MB.  pbuf (N*128 f32) overlaps OFF_GI (gi dead then).

// d_out layout (floats), reference return order
constexpr int DO_MEANS = 0;
constexpr int DO_STD   = B_ * T_ * M_ * 2;
constexpr int DO_LOGW  = DO_STD + B_ * T_ * M_;
constexpr int DO_CORR  = DO_LOGW + B_ * T_ * M_;
constexpr int DO_LAST  = DO_CORR + B_ * T_ * M_;
constexpr int DO_PHI   = DO_LAST + B_ * T_;
} // namespace

// ---------------------------------------------------------------------------
__device__ __forceinline__ float load_agent(const float* p) {
  return __hip_atomic_load(p, __ATOMIC_RELAXED, __HIP_MEMORY_SCOPE_AGENT);
}
__device__ __forceinline__ void store_agent(float* p, float v) {
  __hip_atomic_store(p, v, __ATOMIC_RELAXED, __HIP_MEMORY_SCOPE_AGENT);
}
__device__ __forceinline__ ushort_t f2bf(float f) {
  union { float f; unsigned u; } x{f};
  unsigned r = x.u + 0x7FFFu + ((x.u >> 16) & 1u);
  return (ushort_t)(r >> 16);
}
__device__ __forceinline__ void split2(float f, ushort_t& h, ushort_t& l) {
  h = f2bf(f);
  union { unsigned u; float f; } c;
  c.u = ((unsigned)h) << 16;
  l = f2bf(f - c.f);
}
__device__ __forceinline__ float sigmoidf_(float x) {
  return 1.f / (1.f + __expf(-x));
}

// fence-free grid barrier (relaxed agent atomics; waitcnt drains stores)
__device__ __forceinline__ void grid_barrier(unsigned* cnt, unsigned* gen,
                                             unsigned nblk) {
  __builtin_amdgcn_s_waitcnt(0);
  __syncthreads();
  __atomic_signal_fence(__ATOMIC_SEQ_CST);
  if (threadIdx.x == 0) {
    unsigned g = __hip_atomic_load(gen, __ATOMIC_RELAXED, __HIP_MEMORY_SCOPE_AGENT);
    unsigned a = __hip_atomic_fetch_add(cnt, 1u, __ATOMIC_RELAXED, __HIP_MEMORY_SCOPE_AGENT);
    if (a == nblk - 1u) {
      __hip_atomic_store(cnt, 0u, __ATOMIC_RELAXED, __HIP_MEMORY_SCOPE_AGENT);
      __hip_atomic_store(gen, g + 1u, __ATOMIC_RELAXED, __HIP_MEMORY_SCOPE_AGENT);
    } else {
      while (__hip_atomic_load(gen, __ATOMIC_RELAXED, __HIP_MEMORY_SCOPE_AGENT) == g) {
        __builtin_amdgcn_s_sleep(1);
      }
    }
  }
  __atomic_signal_fence(__ATOMIC_SEQ_CST);
  __syncthreads();
}

// ---------------------------------------------------------------------------
__global__ void init_kernel(float* __restrict__ hbuf, unsigned* __restrict__ bar) {
  int i = blockIdx.x * blockDim.x + threadIdx.x;
  if (i < 2 * B_ * H_) hbuf[i] = 0.f;
  if (i < 2) bar[i] = 0u;
}

// gi0[j][n] = bih0[j] + Wih0[j][0:3] . x[n]
__global__ __launch_bounds__(256)
void pre0_kernel(const float* __restrict__ x, const float* __restrict__ Wih0,
                 const float* __restrict__ bih0, float* __restrict__ gi) {
  size_t idx = (size_t)blockIdx.x * 256 + threadIdx.x;
  if (idx >= (size_t)1200 * N_) return;
  int j = (int)(idx / N_), n = (int)(idx % N_);
  const float* w = Wih0 + (size_t)j * 63;
  const float* xp = x + (size_t)n * 3;
  gi[idx] = bih0[j] + w[0] * xp[0] + w[1] * xp[1] + w[2] * xp[2];
}

// zero feat pad columns [seg*416+400, seg*416+416) for all n, both hi and lo
__global__ void zero_feat_pads(ushort_t* __restrict__ fh, ushort_t* __restrict__ fl) {
  int idx = blockIdx.x * 256 + threadIdx.x;
  if (idx >= N_ * 48) return;
  int n = idx / 48, r = idx % 48;
  size_t o = (size_t)n * FEAT_LD + (r / 16) * SEG + 400 + (r % 16);
  fh[o] = 0; fl[o] = 0;
}

// wx split: [1200][64] = Wih cols {0..3, 403..463}
__global__ void split_wx_kernel(const float* __restrict__ Wih,
                                ushort_t* __restrict__ hi, ushort_t* __restrict__ lo) {
  int idx = blockIdx.x * 256 + threadIdx.x;
  if (idx >= 1200 * INPX_LD) return;
  int j = idx / INPX_LD, k = idx % INPX_LD;
  float v = 0.f;
  if (k < 3)       v = Wih[(size_t)j * 463 + k];
  else if (k < 63) v = Wih[(size_t)j * 463 + 400 + k];
  ushort_t h, l; split2(v, h, l);
  hi[idx] = h; lo[idx] = l;
}

// inpx split: [N][64] = [x(3) | wseq(60) | 0]
__global__ __launch_bounds__(256)
void split_inpx_kernel(const float* __restrict__ x, const float* __restrict__ wseq,
                       ushort_t* __restrict__ hi, ushort_t* __restrict__ lo) {
  size_t idx = (size_t)blockIdx.x * 256 + threadIdx.x;
  if (idx >= (size_t)N_ * INPX_LD) return;
  int n = (int)(idx / INPX_LD), k = (int)(idx % INPX_LD);
  float v = 0.f;
  if (k < 3)       v = x[(size_t)n * 3 + k];
  else if (k < 63) v = wseq[(size_t)n * V_ + (k - 3)];
  ushort_t h, l; split2(v, h, l);
  hi[idx] = h; lo[idx] = l;
}

// wo split: [1200][416] = Wih cols 3..403 (the out_{l-1} block), pad 0
__global__ __launch_bounds__(256)
void split_wo_kernel(const float* __restrict__ Wih,
                     ushort_t* __restrict__ hi, ushort_t* __restrict__ lo) {
  int idx = blockIdx.x * 256 + threadIdx.x;
  if (idx >= 1200 * SEG) return;
  int j = idx / SEG, k = idx % SEG;
  float v = (k < 400) ? Wih[(size_t)j * 463 + 3 + k] : 0.f;
  ushort_t h, l; split2(v, h, l);
  hi[idx] = h; lo[idx] = l;
}

// wh split: [128][1248], cols remapped to feat's [416|416|416] padded layout
__global__ void split_wh_kernel(const float* __restrict__ Wh,
                                ushort_t* __restrict__ hi, ushort_t* __restrict__ lo) {
  int idx = blockIdx.x * 256 + threadIdx.x;
  if (idx >= 128 * FEAT_LD) return;
  int m = idx / FEAT_LD, k = idx % FEAT_LD;
  int seg = k / SEG, off = k % SEG;
  float v = (m < 121 && off < 400) ? Wh[(size_t)m * 1200 + seg * 400 + off] : 0.f;
  ushort_t h, l; split2(v, h, l);
  hi[idx] = h; lo[idx] = l;
}

// ---------------------------------------------------------------------------
// split-bf16 GEMM: C[m][n](or [n][m]) = (Ah+Al)[m][k].(Bh+Bl)[n][k] (3 terms)
//                  + bias[m] (if bias) + Cin[same index] (if Cin)
__global__ __launch_bounds__(256)
void gemm_split_kernel(const ushort_t* __restrict__ Ahi, const ushort_t* __restrict__ Alo,
                       const ushort_t* __restrict__ Bhi, const ushort_t* __restrict__ Blo,
                       const float* __restrict__ bias, const float* __restrict__ Cin,
                       float* __restrict__ C, int mtiles, int ntiles, int ktiles,
                       int strideA, int strideB, int boffB, int Mvalid,
                       int n_major_out, int ldc) {
  int wave = blockIdx.x * 4 + (threadIdx.x >> 6);
  if (wave >= mtiles * ntiles) return;
  int mt = wave / ntiles, nt = wave % ntiles;
  int lane = threadIdx.x & 63, l15 = lane & 15, quad = lane >> 4;
  size_t aoff = (size_t)(mt * 16 + l15) * strideA + quad * 8;
  size_t boff = (size_t)(nt * 16 + l15) * strideB + boffB + quad * 8;
  f32x4 acc = {0.f, 0.f, 0.f, 0.f};
  for (int kt = 0; kt < ktiles; ++kt) {
    bf16x8 ah = *(const bf16x8*)(Ahi + aoff + kt * 32);
    bf16x8 al = *(const bf16x8*)(Alo + aoff + kt * 32);
    bf16x8 bh = *(const bf16x8*)(Bhi + boff + kt * 32);
    bf16x8 bl = *(const bf16x8*)(Blo + boff + kt * 32);
    acc = __builtin_amdgcn_mfma_f32_16x16x32_bf16(ah, bh, acc, 0, 0, 0);
    acc = __builtin_amdgcn_mfma_f32_16x16x32_bf16(ah, bl, acc, 0, 0, 0);
    acc = __builtin_amdgcn_mfma_f32_16x16x32_bf16(al, bh, acc, 0, 0, 0);
  }
  int n = nt * 16 + l15;
#pragma unroll
  for (int r = 0; r < 4; ++r) {
    int m = mt * 16 + quad * 4 + r;
    if (m < Mvalid) {
      float v = acc[r];
      if (bias) v += bias[m];
      size_t o = n_major_out ? (size_t)n * ldc + m : (size_t)m * ldc + n;
      if (Cin) v += Cin[o];
      C[o] = v;
    }
  }
}

// ---------------------------------------------------------------------------
// scan: recurrent gh (+ layer0 w-part) via 3-term split MFMA; gates fp32.
// 100 blocks x 256 threads; block owns 4 hidden units.
// MFMA A-rows (per unit u=0..3): m=u      -> r-gate  [Whh_r | Wih_r w-part]
//                                m=4+u    -> z-gate  [Whh_z | Wih_z w-part]
//                                m=8+u    -> n-gate  [Whh_n | 0]   (inside r*)
//                                m=12+u   -> n-gate  [0     | Wih_n w-part]
//                                            (outside r* — the r3/r4 bug fix)
template <int LAYER>
__global__ __launch_bounds__(256)
void scan_kernel(const float* __restrict__ gi,     // [1200][N] fp32
                 const float* __restrict__ Whh, const float* __restrict__ Wih,
                 const float* __restrict__ bhh,
                 const float* __restrict__ Ww, const float* __restrict__ bw,
                 const int* __restrict__ c,
                 float* __restrict__ wseq,          // [N][60] fp32
                 float* __restrict__ hbuf,          // 2*B*H fp32 ping-pong
                 ushort_t* __restrict__ feat_hi, ushort_t* __restrict__ feat_lo,
                 float* __restrict__ out_phi, unsigned* __restrict__ bar) {
  constexpr int KT = (LAYER == 0) ? 15 : 13;   // K-tiles of 32
  constexpr int KB = KT * 32;                  // 480 / 416
  constexpr int SH = KB + 8;                   // LDS row stride (16B-aligned)

  __shared__ __align__(16) ushort_t hTh[B_ * SH];
  __shared__ __align__(16) ushort_t hTl[B_ * SH];
  __shared__ float sdots[B_][17];
  __shared__ float sbh[12];
  // layer-0 attention scratch
  __shared__ float sh[H_];
  __shared__ float spart[30 * 8];
  __shared__ float sp[30];
  __shared__ float sphi[U_ + 1];
  __shared__ float skap[K_];
  __shared__ int sc[U_];

  const int wg = blockIdx.x, j0 = wg * 4;
  const int tid = threadIdx.x;
  const int waveid = tid >> 6, lane = tid & 63;
  const int l15 = lane & 15, quad = lane >> 4;

  // ---- split weight A-fragments in registers, once ----
  const int m = l15;
  int grow = -1;   // Whh row for k<400
  int wrow = -1;   // Wih w-part row for k in [400,460)  (layer 0 only)
  if (m < 4)       { grow = j0 + m;            wrow = grow; }
  else if (m < 8)  { grow = 400 + j0 + m - 4;  wrow = grow; }
  else if (m < 12) { grow = 800 + j0 + m - 8;  wrow = -1;   }
  else if (LAYER == 0) { wrow = 800 + j0 + m - 12; }
  bf16x8 afh[KT], afl[KT];
#pragma unroll
  for (int kt = 0; kt < KT; ++kt) {
    union { bf16x8 v; ushort_t s[8]; } uh, ul;
#pragma unroll
    for (int j = 0; j < 8; ++j) {
      int k = kt * 32 + quad * 8 + j;
      float val = 0.f;
      if (k < H_) {
        if (grow >= 0) val = Whh[(size_t)grow * H_ + k];
      } else if (LAYER == 0 && k < H_ + V_) {
        if (wrow >= 0) val = Wih[(size_t)wrow * 63 + 3 + (k - H_)];
      }
      ushort_t h, l; split2(val, h, l);
      uh.s[j] = h; ul.s[j] = l;
    }
    afh[kt] = uh.v; afl[kt] = ul.v;
  }

  // ---- one-time LDS init ----
  for (int i = tid; i < B_ * SH; i += 256) { hTh[i] = 0; hTl[i] = 0; }
  if (tid < 12) sbh[tid] = bhh[(tid >> 2) * H_ + j0 + (tid & 3)];
  if constexpr (LAYER == 0) {
    if (wg < B_) {
      for (int i = tid; i < U_; i += 256) sc[i] = c[wg * U_ + i];
      if (tid < K_) skap[tid] = 0.f;
    }
  }
  __syncthreads();

  // ---- time loop ----
  for (int t = 0; t < T_; ++t) {
    const int par = t & 1;
    const float* hprev = hbuf + (size_t)par * B_ * H_;
    float* hnext = hbuf + (size_t)(1 - par) * B_ * H_;

    // stage h_{t-1} (split bf16) into LDS; layer0 also w_{t-1}
    for (int i = tid; i < B_ * H_; i += 256) {
      int b = i / H_, k = i - b * H_;
      ushort_t h, l; split2(load_agent(hprev + i), h, l);
      hTh[b * SH + k] = h; hTl[b * SH + k] = l;
    }
    if constexpr (LAYER == 0) {
      if (t > 0) {
        for (int i = tid; i < B_ * V_; i += 256) {
          int b = i / V_, k = i - b * V_;
          ushort_t h, l;
          split2(load_agent(wseq + ((size_t)b * T_ + (t - 1)) * V_ + k), h, l);
          hTh[b * SH + H_ + k] = h; hTl[b * SH + H_ + k] = l;
        }
      }
    }
    __syncthreads();

    // recurrent split-MFMA: waves 0/1 handle batch halves
    if (waveid < 2) {
      const ushort_t* bh_ = hTh + (waveid * 16 + l15) * SH + quad * 8;
      const ushort_t* bl_ = hTl + (waveid * 16 + l15) * SH + quad * 8;
      f32x4 acc = {0.f, 0.f, 0.f, 0.f};
#pragma unroll
      for (int kt = 0; kt < KT; ++kt) {
        bf16x8 vh = *(const bf16x8*)(bh_ + kt * 32);
        bf16x8 vl = *(const bf16x8*)(bl_ + kt * 32);
        acc = __builtin_amdgcn_mfma_f32_16x16x32_bf16(afh[kt], vh, acc, 0, 0, 0);
        acc = __builtin_amdgcn_mfma_f32_16x16x32_bf16(afh[kt], vl, acc, 0, 0, 0);
        acc = __builtin_amdgcn_mfma_f32_16x16x32_bf16(afl[kt], vh, acc, 0, 0, 0);
      }
      int b = waveid * 16 + l15;
#pragma unroll
      for (int r = 0; r < 4; ++r) sdots[b][quad * 4 + r] = acc[r];
    }
    __syncthreads();

    // gates + state update (128 threads: 32 b x 4 units)
    if (tid < 128) {
      int b = tid & 31, u = tid >> 5;
      int n = b * T_ + t;
      float gr = gi[(size_t)(j0 + u) * GI_LD + n];
      float gz = gi[(size_t)(400 + j0 + u) * GI_LD + n];
      float gn = gi[(size_t)(800 + j0 + u) * GI_LD + n];
      if constexpr (LAYER == 0) gn += sdots[b][12 + u];   // w-part, OUTSIDE r*
      float r = sigmoidf_(gr + sdots[b][u] + sbh[u]);
      float z = sigmoidf_(gz + sdots[b][4 + u] + sbh[4 + u]);
      float nn = tanhf(gn + r * (sdots[b][8 + u] + sbh[8 + u]));
      float hp = load_agent(hprev + (size_t)b * H_ + j0 + u);
      float hv = (1.f - z) * nn + z * hp;
      store_agent(hnext + (size_t)b * H_ + j0 + u, hv);
      ushort_t fh, fl; split2(hv, fh, fl);
      size_t fo = (size_t)n * FEAT_LD + LAYER * SEG + j0 + u;
      feat_hi[fo] = fh; feat_lo[fo] = fl;
    }
    grid_barrier(bar, bar + 1, gridDim.x);

    if constexpr (LAYER == 0) {
      // attention window (fp32): block b in [0,32)
      if (wg < B_) {
        const int b = wg;
        for (int i = tid; i < H_; i += 256)
          sh[i] = load_agent(hnext + (size_t)b * H_ + i);
        __syncthreads();
        if (tid < 240) {
          int mm = tid >> 3, part = tid & 7;
          float acc = 0.f;
          int k0 = part * 50;
          for (int k = k0; k < k0 + 50; ++k) acc = fmaf(sh[k], Ww[mm * H_ + k], acc);
          spart[mm * 8 + part] = acc;
        }
        __syncthreads();
        if (tid < 30) {
          float s = bw[tid];
          for (int i = 0; i < 8; ++i) s += spart[tid * 8 + i];
          sp[tid] = __expf(s);
        }
        __syncthreads();
        if (tid < K_) skap[tid] += sp[20 + tid];
        __syncthreads();
        if (tid < U_ + 1) {
          float uu = (float)tid, s = 0.f;
          for (int k = 0; k < K_; ++k) {
            float diff = skap[k] - uu;
            s = fmaf(sp[k], __expf(-sp[10 + k] * diff * diff), s);
          }
          sphi[tid] = s;
        }
        __syncthreads();
        if (tid < V_) {
          float s = 0.f;
          for (int uu = 0; uu < U_; ++uu)
            if (sc[uu] == tid) s += sphi[uu];
          store_agent(wseq + ((size_t)b * T_ + t) * V_ + tid, s);
        }
        if (t == T_ - 1 && tid < U_ + 1)
          out_phi[b * (U_ + 1) + tid] = sphi[tid];
      }
      grid_barrier(bar, bar + 1, gridDim.x);
    }
  }
}

// ---------------------------------------------------------------------------
__global__ __launch_bounds__(256)
void post_kernel(const float* __restrict__ p, float* __restrict__ dout) {
  int n = blockIdx.x * 256 + threadIdx.x;
  if (n >= N_) return;
  const float* r = p + (size_t)n * 128;
  dout[DO_LAST + n] = r[0];
  float mx = -1e30f;
  for (int m = 0; m < M_; ++m) mx = fmaxf(mx, r[1 + m]);
  float s = 0.f;
  for (int m = 0; m < M_; ++m) s += __expf(r[1 + m] - mx);
  float lse = mx + logf(s);
  for (int m = 0; m < M_; ++m) dout[DO_LOGW + (size_t)n * M_ + m] = r[1 + m] - lse;
  for (int i = 0; i < 2 * M_; ++i) dout[DO_MEANS + (size_t)n * 2 * M_ + i] = r[21 + i];
  for (int m = 0; m < M_; ++m) dout[DO_STD + (size_t)n * M_ + m] = __expf(r[61 + m]);
  for (int m = 0; m < M_; ++m) dout[DO_CORR + (size_t)n * M_ + m] = tanhf(r[81 + m]);
}

// ---------------------------------------------------------------------------
extern "C" void kernel_launch(void* const* d_in, const int* in_sizes, int n_in,
                              void* d_out, int out_size, void* d_ws, size_t ws_size,
                              hipStream_t stream) {
  const float* x    = (const float*)d_in[0];
  const int*   c    = (const int*)d_in[1];
  const float* Wih0 = (const float*)d_in[2];
  const float* Whh0 = (const float*)d_in[3];
  const float* bih0 = (const float*)d_in[4];
  const float* bhh0 = (const float*)d_in[5];
  const float* Wih1 = (const float*)d_in[6];
  const float* Whh1 = (const float*)d_in[7];
  const float* bih1 = (const float*)d_in[8];
  const float* bhh1 = (const float*)d_in[9];
  const float* Wih2 = (const float*)d_in[10];
  const float* Whh2 = (const float*)d_in[11];
  const float* bih2 = (const float*)d_in[12];
  const float* bhh2 = (const float*)d_in[13];
  const float* Ww   = (const float*)d_in[14];
  const float* bw   = (const float*)d_in[15];
  const float* Wh   = (const float*)d_in[16];
  const float* bh   = (const float*)d_in[17];
  (void)in_sizes; (void)n_in; (void)out_size; (void)ws_size;

  float* ws = (float*)d_ws;
  float*    gi    = ws + OFF_GI;
  float*    wseq  = ws + OFF_WSEQ;
  float*    hbuf  = ws + OFF_H;
  unsigned* bar   = (unsigned*)(ws + OFF_BAR);
  ushort_t* fh    = (ushort_t*)(ws + OFF_FEATH);
  ushort_t* fl    = (ushort_t*)(ws + OFF_FEATL);
  ushort_t* ixh   = (ushort_t*)(ws + OFF_INPXH);
  ushort_t* ixl   = (ushort_t*)(ws + OFF_INPXL);
  ushort_t* wxh   = (ushort_t*)(ws + OFF_WXH);
  ushort_t* wxl   = (ushort_t*)(ws + OFF_WXL);
  ushort_t* woh   = (ushort_t*)(ws + OFF_WOH);
  ushort_t* wol   = (ushort_t*)(ws + OFF_WOL);
  ushort_t* whh_  = (ushort_t*)(ws + OFF_WHH);
  ushort_t* whl_  = (ushort_t*)(ws + OFF_WHL);
  float*    pbuf  = ws + OFF_GI;   // overlaps gi (dead after scan<2>)
  float*    dout  = (float*)d_out;

  const dim3 blk(256);
  const int NT = N_ / 16;  // 1024 n-tiles

  // --- layer 0 ---
  init_kernel<<<dim3(100), blk, 0, stream>>>(hbuf, bar);
  pre0_kernel<<<dim3((int)(((size_t)1200 * N_) / 256)), blk, 0, stream>>>(x, Wih0, bih0, gi);
  zero_feat_pads<<<dim3((N_ * 48) / 256), blk, 0, stream>>>(fh, fl);
  scan_kernel<0><<<dim3(100), blk, 0, stream>>>(gi, Whh0, Wih0, bhh0, Ww, bw, c,
                                                wseq, hbuf, fh, fl, dout + DO_PHI, bar);
  // shared input-x/wseq split (same for layers 1 and 2)
  split_inpx_kernel<<<dim3((N_ * INPX_LD) / 256), blk, 0, stream>>>(x, wseq, ixh, ixl);

  // --- layer 1 ---
  split_wx_kernel<<<dim3((1200 * INPX_LD) / 256), blk, 0, stream>>>(Wih1, wxh, wxl);
  gemm_split_kernel<<<dim3(75 * NT / 4), blk, 0, stream>>>(
      wxh, wxl, ixh, ixl, bih1, nullptr, gi, 75, NT, 2, INPX_LD, INPX_LD, 0,
      1200, 0, GI_LD);
  split_wo_kernel<<<dim3((1200 * SEG) / 256), blk, 0, stream>>>(Wih1, woh, wol);
  gemm_split_kernel<<<dim3(75 * NT / 4), blk, 0, stream>>>(
      woh, wol, fh, fl, nullptr, gi, gi, 75, NT, 13, SEG, FEAT_LD, 0 * SEG,
      1200, 0, GI_LD);
  init_kernel<<<dim3(100), blk, 0, stream>>>(hbuf, bar);
  scan_kernel<1><<<dim3(100), blk, 0, stream>>>(gi, Whh1, Wih1, bhh1, Ww, bw, c,
                                                wseq, hbuf, fh, fl, nullptr, bar);
  // --- layer 2 ---
  split_wx_kernel<<<dim3((1200 * INPX_LD) / 256), blk, 0, stream>>>(Wih2, wxh, wxl);
  gemm_split_kernel<<<dim3(75 * NT / 4), blk, 0, stream>>>(
      wxh, wxl, ixh, ixl, bih2, nullptr, gi, 75, NT, 2, INPX_LD, INPX_LD, 0,
      1200, 0, GI_LD);
  split_wo_kernel<<<dim3((1200 * SEG) / 256), blk, 0, stream>>>(Wih2, woh, wol);
  gemm_split_kernel<<<dim3(75 * NT / 4), blk, 0, stream>>>(
      woh, wol, fh, fl, nullptr, gi, gi, 75, NT, 13, SEG, FEAT_LD, 1 * SEG,
      1200, 0, GI_LD);
  init_kernel<<<dim3(100), blk, 0, stream>>>(hbuf, bar);
  scan_kernel<2><<<dim3(100), blk, 0, stream>>>(gi, Whh2, Wih2, bhh2, Ww, bw, c,
                                                wseq, hbuf, fh, fl, nullptr, bar);
  // --- head ---
  split_wh_kernel<<<dim3((128 * FEAT_LD) / 256), blk, 0, stream>>>(Wh, whh_, whl_);
  gemm_split_kernel<<<dim3(8 * NT / 4), blk, 0, stream>>>(
      whh_, whl_, fh, fl, bh, nullptr, pbuf, 8, NT, FEAT_LD / 32, FEAT_LD,
      FEAT_LD, 0, 121, 1, 128);
  post_kernel<<<dim3(N_ / 256), blk, 0, stream>>>(pbuf, dout);
}

// Round 7
// 18466.284 us; speedup vs baseline: 4.8360x; 1.7802x over previous
//
#include <hip/hip_runtime.h>
#include <cmath>

// ---------------------------------------------------------------------------
// Graves handwriting synthesis: 3-layer GRU + attention window + MDN head
// B=32 T=512 U=64 V=60 H=400 K=10 M=20 IN=3
//
// Round 7: round-6 fused pipeline + attention p-MFMA row fix.
//  BUG in r6: p has 30 rows but one 16x16 MFMA yields 16 D-rows; sp[16..29]
//  (beta, dkappa) was read uninitialized -> exp(garbage) -> NaN cascade.
//  FIX: waves 0 and 1 each compute 16 p-rows (A row = waveid*16 + lane&15,
//  rows >=30 zero); store sp[sample][waveid*16 + quad*4 + r].
//
//  Structure (from r6): ONE persistent kernel, 514 grid-barrier intervals;
//  interval i runs L0(t=i) || L1(t=i-1) || L2(t=i-2) on 150 blocks
//  (3 layers x 25 unit-slices x 2 batch-halves). Attention replicated per
//  L0/L1 block (no w-exchange barrier). All input-side dots + biases folded
//  into the main MFMA K ([h | h_prev | w | x | 1]); n-gate input part on
//  spare rows 12..15 (outside r). h via fp32 rings + relaxed agent atomics.
// ---------------------------------------------------------------------------

typedef __attribute__((ext_vector_type(8))) short bf16x8;
typedef __attribute__((ext_vector_type(4))) float f32x4;
typedef unsigned short ushort_t;

namespace {
constexpr int B_ = 32, T_ = 512, U_ = 64, V_ = 60, H_ = 400, K_ = 10, M_ = 20;
constexpr int N_ = B_ * T_;          // 16384
constexpr int SEG = 416, FEAT_LD = 1248;
constexpr int NBLK = 150;
constexpr int SBL = 872;             // B-row stride in LDS (u16), 16B-aligned

// workspace layout (float indices)
constexpr size_t OFF_R0    = 0;                       // 4*32*400 per ring
constexpr size_t OFF_R1    = 51200;
constexpr size_t OFF_R2    = 102400;
constexpr size_t OFF_WRING = 153600;                  // 4*32*60
constexpr size_t OFF_BAR   = 161280;                  // 2 uints (zero 16)
constexpr size_t ZERO_TOT  = 161296;
constexpr size_t OFF_FEATH = 161296;                  // N*1248 bf16
constexpr size_t OFF_FEATL = OFF_FEATH + (size_t)N_ * FEAT_LD / 2;
constexpr size_t OFF_WHH   = OFF_FEATL + (size_t)N_ * FEAT_LD / 2;  // 128*1248 bf16
constexpr size_t OFF_WHL   = OFF_WHH + (size_t)128 * FEAT_LD / 2;
constexpr size_t OFF_P     = OFF_WHL + (size_t)128 * FEAT_LD / 2;   // N*128 f32
// total ~22.9M floats ~92 MB

// d_out layout (floats), reference return order
constexpr int DO_MEANS = 0;
constexpr int DO_STD   = B_ * T_ * M_ * 2;
constexpr int DO_LOGW  = DO_STD + B_ * T_ * M_;
constexpr int DO_CORR  = DO_LOGW + B_ * T_ * M_;
constexpr int DO_LAST  = DO_CORR + B_ * T_ * M_;
constexpr int DO_PHI   = DO_LAST + B_ * T_;
} // namespace

// ---------------------------------------------------------------------------
__device__ __forceinline__ float load_agent(const float* p) {
  return __hip_atomic_load(p, __ATOMIC_RELAXED, __HIP_MEMORY_SCOPE_AGENT);
}
__device__ __forceinline__ void store_agent(float* p, float v) {
  __hip_atomic_store(p, v, __ATOMIC_RELAXED, __HIP_MEMORY_SCOPE_AGENT);
}
__device__ __forceinline__ ushort_t f2bf(float f) {
  union { float f; unsigned u; } x{f};
  unsigned r = x.u + 0x7FFFu + ((x.u >> 16) & 1u);
  return (ushort_t)(r >> 16);
}
__device__ __forceinline__ void split2(float f, ushort_t& h, ushort_t& l) {
  h = f2bf(f);
  union { unsigned u; float f; } c;
  c.u = ((unsigned)h) << 16;
  l = f2bf(f - c.f);
}
__device__ __forceinline__ float bfpair(ushort_t h, ushort_t l) {
  union { unsigned u; float f; } a, b;
  a.u = ((unsigned)h) << 16; b.u = ((unsigned)l) << 16;
  return a.f + b.f;
}
__device__ __forceinline__ float sigmoidf_(float x) {
  return 1.f / (1.f + __expf(-x));
}

// fence-free grid barrier (relaxed agent atomics; waitcnt drains stores)
__device__ __forceinline__ void grid_barrier(unsigned* cnt, unsigned* gen,
                                             unsigned nblk) {
  __builtin_amdgcn_s_waitcnt(0);
  __syncthreads();
  __atomic_signal_fence(__ATOMIC_SEQ_CST);
  if (threadIdx.x == 0) {
    unsigned g = __hip_atomic_load(gen, __ATOMIC_RELAXED, __HIP_MEMORY_SCOPE_AGENT);
    unsigned a = __hip_atomic_fetch_add(cnt, 1u, __ATOMIC_RELAXED, __HIP_MEMORY_SCOPE_AGENT);
    if (a == nblk - 1u) {
      __hip_atomic_store(cnt, 0u, __ATOMIC_RELAXED, __HIP_MEMORY_SCOPE_AGENT);
      __hip_atomic_store(gen, g + 1u, __ATOMIC_RELAXED, __HIP_MEMORY_SCOPE_AGENT);
    } else {
      while (__hip_atomic_load(gen, __ATOMIC_RELAXED, __HIP_MEMORY_SCOPE_AGENT) == g) {
        __builtin_amdgcn_s_sleep(1);
      }
    }
  }
  __atomic_signal_fence(__ATOMIC_SEQ_CST);
  __syncthreads();
}

// ---------------------------------------------------------------------------
__global__ __launch_bounds__(256)
void zero_ws(float* __restrict__ p) {
  size_t i = (size_t)blockIdx.x * 256 + threadIdx.x;
  if (i < ZERO_TOT) p[i] = 0.f;
}

__global__ void zero_feat_pads(ushort_t* __restrict__ fh, ushort_t* __restrict__ fl) {
  int idx = blockIdx.x * 256 + threadIdx.x;
  if (idx >= N_ * 48) return;
  int n = idx / 48, r = idx % 48;
  size_t o = (size_t)n * FEAT_LD + (r / 16) * SEG + 400 + (r % 16);
  fh[o] = 0; fl[o] = 0;
}

// wh split: [128][1248], cols remapped to feat's [416|416|416] padded layout
__global__ void split_wh_kernel(const float* __restrict__ Wh,
                                ushort_t* __restrict__ hi, ushort_t* __restrict__ lo) {
  int idx = blockIdx.x * 256 + threadIdx.x;
  if (idx >= 128 * FEAT_LD) return;
  int m = idx / FEAT_LD, k = idx % FEAT_LD;
  int seg = k / SEG, off = k % SEG;
  float v = (m < 121 && off < 400) ? Wh[(size_t)m * 1200 + seg * 400 + off] : 0.f;
  ushort_t h, l; split2(v, h, l);
  hi[idx] = h; lo[idx] = l;
}

// split-bf16 head GEMM (r5-verified)
__global__ __launch_bounds__(256)
void gemm_split_kernel(const ushort_t* __restrict__ Ahi, const ushort_t* __restrict__ Alo,
                       const ushort_t* __restrict__ Bhi, const ushort_t* __restrict__ Blo,
                       const float* __restrict__ bias, float* __restrict__ C,
                       int mtiles, int ntiles, int ktiles, int strideA, int strideB,
                       int Mvalid, int ldc) {
  int wave = blockIdx.x * 4 + (threadIdx.x >> 6);
  if (wave >= mtiles * ntiles) return;
  int mt = wave / ntiles, nt = wave % ntiles;
  int lane = threadIdx.x & 63, l15 = lane & 15, quad = lane >> 4;
  size_t aoff = (size_t)(mt * 16 + l15) * strideA + quad * 8;
  size_t boff = (size_t)(nt * 16 + l15) * strideB + quad * 8;
  f32x4 acc = {0.f, 0.f, 0.f, 0.f};
  for (int kt = 0; kt < ktiles; ++kt) {
    bf16x8 ah = *(const bf16x8*)(Ahi + aoff + kt * 32);
    bf16x8 al = *(const bf16x8*)(Alo + aoff + kt * 32);
    bf16x8 bh = *(const bf16x8*)(Bhi + boff + kt * 32);
    bf16x8 bl = *(const bf16x8*)(Blo + boff + kt * 32);
    acc = __builtin_amdgcn_mfma_f32_16x16x32_bf16(ah, bh, acc, 0, 0, 0);
    acc = __builtin_amdgcn_mfma_f32_16x16x32_bf16(ah, bl, acc, 0, 0, 0);
    acc = __builtin_amdgcn_mfma_f32_16x16x32_bf16(al, bh, acc, 0, 0, 0);
  }
  int n = nt * 16 + l15;
#pragma unroll
  for (int r = 0; r < 4; ++r) {
    int m = mt * 16 + quad * 4 + r;
    if (m < Mvalid) C[(size_t)n * ldc + m] = acc[r] + bias[m];
  }
}

// ---------------------------------------------------------------------------
// fused pipelined scan body (templated per layer)
template <int L>
__device__ __forceinline__ void scan_body(
    int slice, int bhalf, int bx,
    const float* __restrict__ x, const int* __restrict__ c,
    const float* __restrict__ Wih, const float* __restrict__ Whh,
    const float* __restrict__ bih, const float* __restrict__ bhh,
    const float* __restrict__ Ww, const float* __restrict__ bw,
    float* __restrict__ ringS, const float* __restrict__ ringP,
    const float* __restrict__ wring_c, float* __restrict__ wring_w,
    ushort_t* __restrict__ fh, ushort_t* __restrict__ fl,
    float* __restrict__ out_phi, unsigned* __restrict__ bar,
    ushort_t* Bh, ushort_t* Bl, float (*su)[65], float (*sp)[33],
    float (*skap)[10], unsigned char (*sc)[64]) {
  constexpr int KT = (L == 0) ? 15 : 27;
  constexpr int CONST_K = (L == 0) ? 463 : 863;
  constexpr int XOFF = (L == 0) ? 460 : 860;
  constexpr int WOFF = (L == 0) ? 400 : 800;
  constexpr int IW = (L == 0) ? 63 : 463;
  const int tid = threadIdx.x;
  const int waveid = tid >> 6, lane = tid & 63;
  const int l15 = lane & 15, quad = lane >> 4;
  const int rt = waveid;                 // rowtile 0..3
  const int m = l15;
  const int uu = m & 3, gate = m >> 2;   // 0=r 1=z 2=hn 3=inn
  const int J = slice * 16 + rt * 4 + uu;
  const int B0 = bhalf * 16;             // first global sample of this block

  // ---- main A-fragments (split bf16), in registers for all 512 steps ----
  bf16x8 afh[KT], afl[KT];
#pragma unroll
  for (int kt = 0; kt < KT; ++kt) {
    union { bf16x8 v; ushort_t s[8]; } uh, ul;
#pragma unroll
    for (int j = 0; j < 8; ++j) {
      int k = kt * 32 + quad * 8 + j;
      float v = 0.f;
      if (k < 400) {
        if (gate == 0)      v = Whh[(size_t)J * 400 + k];
        else if (gate == 1) v = Whh[(size_t)(400 + J) * 400 + k];
        else if (gate == 2) v = Whh[(size_t)(800 + J) * 400 + k];
      } else if (k < CONST_K) {
        int col;
        if (L == 0) col = (k < 460) ? 3 + (k - 400) : (k - 460);
        else        col = (k < 800) ? 3 + (k - 400)
                        : (k < 860) ? 403 + (k - 800) : (k - 860);
        if (gate == 0)      v = Wih[(size_t)J * IW + col];
        else if (gate == 1) v = Wih[(size_t)(400 + J) * IW + col];
        else if (gate == 3) v = Wih[(size_t)(800 + J) * IW + col];
      } else if (k == CONST_K) {
        if (gate == 0)      v = bih[J] + bhh[J];
        else if (gate == 1) v = bih[400 + J] + bhh[400 + J];
        else if (gate == 2) v = bhh[800 + J];
        else                v = bih[800 + J];
      }
      ushort_t h, l; split2(v, h, l);
      uh.s[j] = h; ul.s[j] = l;
    }
    afh[kt] = uh.v; afl[kt] = ul.v;
  }

  // ---- attention p-fragments (Ww rows, split), L0/L1 only ----
  // FIX(r7): waves 0/1 each own 16 p-rows: prow = waveid*16 + l15 (<30 valid)
  bf16x8 apfh[14], apfl[14];
  if constexpr (L <= 1) {
    const int prow = (waveid < 2) ? (waveid * 16 + l15) : 32;
#pragma unroll
    for (int pk = 0; pk < 14; ++pk) {
      int kt = (pk < 13) ? ((L == 0) ? pk : 12 + pk) : ((L == 0) ? 14 : 26);
      union { bf16x8 v; ushort_t s[8]; } uh, ul;
#pragma unroll
      for (int j = 0; j < 8; ++j) {
        int k = kt * 32 + quad * 8 + j;
        int col = k - ((L == 0) ? 0 : 400);
        float v = 0.f;
        if (prow < 30) {
          if (col >= 0 && col < 400) v = Ww[prow * 400 + col];
          else if (k == CONST_K)     v = bw[prow];
        }
        ushort_t h, l; split2(v, h, l);
        uh.s[j] = h; ul.s[j] = l;
      }
      apfh[pk] = uh.v; apfl[pk] = ul.v;
    }
  }

  // ---- one-time LDS init ----
  for (int i = tid; i < 16 * SBL; i += 256) { Bh[i] = 0; Bl[i] = 0; }
  for (int i = tid; i < 160; i += 256) skap[i / 10][i % 10] = 0.f;
  if constexpr (L <= 1) {
    for (int i = tid; i < 16 * 64; i += 256)
      sc[i >> 6][i & 63] = (unsigned char)c[(B0 + (i >> 6)) * U_ + (i & 63)];
  }
  __syncthreads();
  if (tid < 16) Bh[tid * SBL + CONST_K] = 0x3F80;  // bf16(1.0); lo stays 0
  __syncthreads();

  // ---- pipelined time loop ----
  for (int iv = 0; iv < 514; ++iv) {
    int t = iv - L;
    if (t >= 0 && t < T_) {
      // -- staging: own h(t-1); L>=1 also h_prev(t); L2 also w(t); x(t) --
      {
        const float* src = ringS + (size_t)((t + 3) & 3) * 12800 + B0 * 400;
        for (int idx = tid; idx < 6400; idx += 256) {
          int b = idx / 400, k = idx - b * 400;
          ushort_t h, l; split2(load_agent(src + idx), h, l);
          Bh[b * SBL + k] = h; Bl[b * SBL + k] = l;
        }
      }
      if constexpr (L >= 1) {
        const float* src = ringP + (size_t)(t & 3) * 12800 + B0 * 400;
        for (int idx = tid; idx < 6400; idx += 256) {
          int b = idx / 400, k = idx - b * 400;
          ushort_t h, l; split2(load_agent(src + idx), h, l);
          Bh[b * SBL + 400 + k] = h; Bl[b * SBL + 400 + k] = l;
        }
      }
      if constexpr (L == 2) {
        const float* src = wring_c + (size_t)(t & 3) * 1920 + B0 * 60;
        for (int idx = tid; idx < 960; idx += 256) {
          int b = idx / 60, v = idx - b * 60;
          ushort_t h, l; split2(load_agent(src + idx), h, l);
          Bh[b * SBL + WOFF + v] = h; Bl[b * SBL + WOFF + v] = l;
        }
      }
      if (tid < 48) {
        int b = tid / 3, xc = tid - b * 3;
        ushort_t h, l;
        split2(x[((size_t)(B0 + b) * T_ + t) * 3 + xc], h, l);
        Bh[b * SBL + XOFF + xc] = h; Bl[b * SBL + XOFF + xc] = l;
      }
      __syncthreads();

      // -- attention (L0 computes w(t-1); L1 computes w(t)) --
      if constexpr (L <= 1) {
        const bool dow = (L == 1) || (t > 0);
        if (dow) {
          if (waveid < 2) {  // p-MFMA: rows waveid*16..+15 of 30, cols 16
            f32x4 acc = {0.f, 0.f, 0.f, 0.f};
            const int brow = l15 * SBL + quad * 8;
#pragma unroll
            for (int pk = 0; pk < 14; ++pk) {
              int kt = (pk < 13) ? ((L == 0) ? pk : 12 + pk) : ((L == 0) ? 14 : 26);
              bf16x8 bh8 = *(const bf16x8*)(Bh + brow + kt * 32);
              bf16x8 bl8 = *(const bf16x8*)(Bl + brow + kt * 32);
              acc = __builtin_amdgcn_mfma_f32_16x16x32_bf16(apfh[pk], bh8, acc, 0, 0, 0);
              acc = __builtin_amdgcn_mfma_f32_16x16x32_bf16(apfh[pk], bl8, acc, 0, 0, 0);
              acc = __builtin_amdgcn_mfma_f32_16x16x32_bf16(apfl[pk], bh8, acc, 0, 0, 0);
            }
#pragma unroll
            for (int r = 0; r < 4; ++r)
              sp[l15][waveid * 16 + quad * 4 + r] = acc[r];
          }
          __syncthreads();
          for (int idx = tid; idx < 480; idx += 256) {     // exp(p)
            int b = idx / 30, mm = idx - b * 30;
            sp[b][mm] = __expf(sp[b][mm]);
          }
          __syncthreads();
          for (int idx = tid; idx < 160; idx += 256) {     // kappa += dk
            int b = idx / 10, k2 = idx - b * 10;
            skap[b][k2] += sp[b][20 + k2];
          }
          __syncthreads();
          for (int idx = tid; idx < 1040; idx += 256) {    // phi
            int b = idx / 65, u = idx - b * 65;
            float s = 0.f;
#pragma unroll
            for (int k2 = 0; k2 < 10; ++k2) {
              float d = skap[b][k2] - (float)u;
              s = fmaf(sp[b][k2], __expf(-sp[b][10 + k2] * d * d), s);
            }
            su[b][u] = s;
          }
          __syncthreads();
          const int wt = (L == 0) ? t - 1 : t;
          for (int idx = tid; idx < 960; idx += 256) {     // w gather
            int b = idx / 60, v = idx - b * 60;
            float s = 0.f;
#pragma unroll 8
            for (int u = 0; u < U_; ++u)
              s += (sc[b][u] == v) ? su[b][u] : 0.f;
            ushort_t h, l; split2(s, h, l);
            Bh[b * SBL + WOFF + v] = h; Bl[b * SBL + WOFF + v] = l;
            if (L == 0 && slice == 0)
              store_agent(wring_w + (size_t)(wt & 3) * 1920 + B0 * 60 + idx, s);
          }
          if (L == 1 && t == T_ - 1 && slice == 0) {
            for (int idx = tid; idx < 1040; idx += 256)
              out_phi[(B0 + idx / 65) * 65 + (idx % 65)] = su[idx / 65][idx % 65];
          }
          __syncthreads();
        }
      }

      // -- main MFMA: rows = this wave's rowtile, cols = 16 samples --
      {
        f32x4 acc = {0.f, 0.f, 0.f, 0.f};
        const int brow = l15 * SBL + quad * 8;
#pragma unroll
        for (int kt = 0; kt < KT; ++kt) {
          bf16x8 bh8 = *(const bf16x8*)(Bh + brow + kt * 32);
          bf16x8 bl8 = *(const bf16x8*)(Bl + brow + kt * 32);
          acc = __builtin_amdgcn_mfma_f32_16x16x32_bf16(afh[kt], bh8, acc, 0, 0, 0);
          acc = __builtin_amdgcn_mfma_f32_16x16x32_bf16(afh[kt], bl8, acc, 0, 0, 0);
          acc = __builtin_amdgcn_mfma_f32_16x16x32_bf16(afl[kt], bh8, acc, 0, 0, 0);
        }
#pragma unroll
        for (int r = 0; r < 4; ++r)
          su[l15][rt * 16 + quad * 4 + r] = acc[r];   // su as sdots
      }
      __syncthreads();

      // -- combine: 256 threads = 16 units x 16 samples --
      {
        int b = tid & 15, u = tid >> 4;
        int urt = u >> 2, u3 = u & 3;
        float rr = sigmoidf_(su[b][urt * 16 + 0 * 4 + u3]);
        float zz = sigmoidf_(su[b][urt * 16 + 1 * 4 + u3]);
        float hn = su[b][urt * 16 + 2 * 4 + u3];
        float inn = su[b][urt * 16 + 3 * 4 + u3];
        int Jc = slice * 16 + u;
        float hold = bfpair(Bh[b * SBL + Jc], Bl[b * SBL + Jc]);
        float hv = (1.f - zz) * tanhf(inn + rr * hn) + zz * hold;
        store_agent(ringS + (size_t)(t & 3) * 12800 + (B0 + b) * 400 + Jc, hv);
        int n = (B0 + b) * T_ + t;
        ushort_t hh, hl; split2(hv, hh, hl);
        size_t fo = (size_t)n * FEAT_LD + L * SEG + Jc;
        fh[fo] = hh; fl[fo] = hl;
      }
    }
    grid_barrier(bar, bar + 1, NBLK);
  }
  (void)bx;
}

__global__ __launch_bounds__(256, 1)
void fused_scan(const float* __restrict__ x, const int* __restrict__ c,
                const float* Wih0, const float* Whh0, const float* bih0, const float* bhh0,
                const float* Wih1, const float* Whh1, const float* bih1, const float* bhh1,
                const float* Wih2, const float* Whh2, const float* bih2, const float* bhh2,
                const float* __restrict__ Ww, const float* __restrict__ bw,
                float* ring0, float* ring1, float* ring2, float* wring,
                ushort_t* __restrict__ fh, ushort_t* __restrict__ fl,
                float* __restrict__ out_phi, unsigned* __restrict__ bar) {
  __shared__ ushort_t Bh[16 * SBL];
  __shared__ ushort_t Bl[16 * SBL];
  __shared__ float su[16][65];     // sdots (64 rows) UNION sphi (65)
  __shared__ float sp[16][33];     // attention p (exp'ed); rows 30,31 unused
  __shared__ float skap[16][10];
  __shared__ unsigned char sc[16][64];

  const int bx = blockIdx.x;
  const int grp = bx / 50, r = bx % 50;
  const int slice = r >> 1, bhalf = r & 1;

  if (grp == 0)
    scan_body<0>(slice, bhalf, bx, x, c, Wih0, Whh0, bih0, bhh0, Ww, bw,
                 ring0, nullptr, nullptr, wring, fh, fl, out_phi, bar,
                 Bh, Bl, su, sp, skap, sc);
  else if (grp == 1)
    scan_body<1>(slice, bhalf, bx, x, c, Wih1, Whh1, bih1, bhh1, Ww, bw,
                 ring1, ring0, nullptr, nullptr, fh, fl, out_phi, bar,
                 Bh, Bl, su, sp, skap, sc);
  else
    scan_body<2>(slice, bhalf, bx, x, c, Wih2, Whh2, bih2, bhh2, Ww, bw,
                 ring2, ring1, wring, nullptr, fh, fl, out_phi, bar,
                 Bh, Bl, su, sp, skap, sc);
}

// ---------------------------------------------------------------------------
__global__ __launch_bounds__(256)
void post_kernel(const float* __restrict__ p, float* __restrict__ dout) {
  int n = blockIdx.x * 256 + threadIdx.x;
  if (n >= N_) return;
  const float* r = p + (size_t)n * 128;
  dout[DO_LAST + n] = r[0];
  float mx = -1e30f;
  for (int m = 0; m < M_; ++m) mx = fmaxf(mx, r[1 + m]);
  float s = 0.f;
  for (int m = 0; m < M_; ++m) s += __expf(r[1 + m] - mx);
  float lse = mx + logf(s);
  for (int m = 0; m < M_; ++m) dout[DO_LOGW + (size_t)n * M_ + m] = r[1 + m] - lse;
  for (int i = 0; i < 2 * M_; ++i) dout[DO_MEANS + (size_t)n * 2 * M_ + i] = r[21 + i];
  for (int m = 0; m < M_; ++m) dout[DO_STD + (size_t)n * M_ + m] = __expf(r[61 + m]);
  for (int m = 0; m < M_; ++m) dout[DO_CORR + (size_t)n * M_ + m] = tanhf(r[81 + m]);
}

// ---------------------------------------------------------------------------
extern "C" void kernel_launch(void* const* d_in, const int* in_sizes, int n_in,
                              void* d_out, int out_size, void* d_ws, size_t ws_size,
                              hipStream_t stream) {
  const float* x    = (const float*)d_in[0];
  const int*   c    = (const int*)d_in[1];
  const float* Wih0 = (const float*)d_in[2];
  const float* Whh0 = (const float*)d_in[3];
  const float* bih0 = (const float*)d_in[4];
  const float* bhh0 = (const float*)d_in[5];
  const float* Wih1 = (const float*)d_in[6];
  const float* Whh1 = (const float*)d_in[7];
  const float* bih1 = (const float*)d_in[8];
  const float* bhh1 = (const float*)d_in[9];
  const float* Wih2 = (const float*)d_in[10];
  const float* Whh2 = (const float*)d_in[11];
  const float* bih2 = (const float*)d_in[12];
  const float* bhh2 = (const float*)d_in[13];
  const float* Ww   = (const float*)d_in[14];
  const float* bw   = (const float*)d_in[15];
  const float* Wh   = (const float*)d_in[16];
  const float* bh   = (const float*)d_in[17];
  (void)in_sizes; (void)n_in; (void)out_size; (void)ws_size;

  float* ws = (float*)d_ws;
  float*    ring0 = ws + OFF_R0;
  float*    ring1 = ws + OFF_R1;
  float*    ring2 = ws + OFF_R2;
  float*    wring = ws + OFF_WRING;
  unsigned* bar   = (unsigned*)(ws + OFF_BAR);
  ushort_t* fh    = (ushort_t*)(ws + OFF_FEATH);
  ushort_t* fl    = (ushort_t*)(ws + OFF_FEATL);
  ushort_t* whh_  = (ushort_t*)(ws + OFF_WHH);
  ushort_t* whl_  = (ushort_t*)(ws + OFF_WHL);
  float*    pbuf  = ws + OFF_P;
  float*    dout  = (float*)d_out;

  const dim3 blk(256);

  zero_ws<<<dim3((int)((ZERO_TOT + 255) / 256)), blk, 0, stream>>>(ws);
  zero_feat_pads<<<dim3((N_ * 48) / 256), blk, 0, stream>>>(fh, fl);
  split_wh_kernel<<<dim3((128 * FEAT_LD) / 256), blk, 0, stream>>>(Wh, whh_, whl_);

  fused_scan<<<dim3(NBLK), blk, 0, stream>>>(
      x, c, Wih0, Whh0, bih0, bhh0, Wih1, Whh1, bih1, bhh1,
      Wih2, Whh2, bih2, bhh2, Ww, bw,
      ring0, ring1, ring2, wring, fh, fl, dout + DO_PHI, bar);

  gemm_split_kernel<<<dim3(8 * (N_ / 16) / 4), blk, 0, stream>>>(
      whh_, whl_, fh, fl, bh, pbuf, 8, N_ / 16, FEAT_LD / 32,
      FEAT_LD, FEAT_LD, 121, 128);
  post_kernel<<<dim3(N_ / 256), blk, 0, stream>>>(pbuf, dout);
}

// Round 8
// 14611.746 us; speedup vs baseline: 6.1117x; 1.2638x over previous
//
#include <hip/hip_runtime.h>
#include <cmath>

// ---------------------------------------------------------------------------
// Graves handwriting synthesis: 3-layer GRU + attention window + MDN head
// B=32 T=512 U=64 V=60 H=400 K=10 M=20 IN=3
//
// Round 8: r7 fused pipeline + barrier/staging latency attack.
//  - Hierarchical grid barrier: 15 groups x 10 blocks (padded counter lines)
//    -> ~10 serialized RMWs per line instead of 150 on one line.
//  - Rings store PACKED split-bf16 (u32 = hi<<16 | lo). Staging loads u64
//    relaxed agent atomics (global_load_dwordx2 sc0 sc1): 4x fewer vmem ops,
//    zero consumer split2 VALU, paired ds_write_b32 (no b16 scatter).
//  - Combine lane map swapped (unit fastest) so ring/feat stores coalesce.
//  Math identical to r7 (passed, absmax 0.031).
// ---------------------------------------------------------------------------

typedef __attribute__((ext_vector_type(8))) short bf16x8;
typedef __attribute__((ext_vector_type(4))) float f32x4;
typedef unsigned short ushort_t;

namespace {
constexpr int B_ = 32, T_ = 512, U_ = 64, V_ = 60, H_ = 400, K_ = 10, M_ = 20;
constexpr int N_ = B_ * T_;          // 16384
constexpr int SEG = 416, FEAT_LD = 1248;
constexpr int NBLK = 150;
constexpr int NGRP = 15, GRPSZ = 10;
constexpr int SBL = 872;             // B-row stride in LDS (u16), 16B-aligned

// workspace layout (float indices)
constexpr size_t OFF_R0    = 0;                       // 4*32*400 u32 per ring
constexpr size_t OFF_R1    = 51200;
constexpr size_t OFF_R2    = 102400;
constexpr size_t OFF_WRING = 153600;                  // 4*32*60 f32
constexpr size_t OFF_BAR   = 161280;                  // 1088 uints padded
constexpr size_t ZERO_TOT  = OFF_BAR + 1088;
constexpr size_t OFF_FEATH = ZERO_TOT;                // N*1248 bf16
constexpr size_t OFF_FEATL = OFF_FEATH + (size_t)N_ * FEAT_LD / 2;
constexpr size_t OFF_WHH   = OFF_FEATL + (size_t)N_ * FEAT_LD / 2;  // 128*1248 bf16
constexpr size_t OFF_WHL   = OFF_WHH + (size_t)128 * FEAT_LD / 2;
constexpr size_t OFF_P     = OFF_WHL + (size_t)128 * FEAT_LD / 2;   // N*128 f32

// d_out layout (floats), reference return order
constexpr int DO_MEANS = 0;
constexpr int DO_STD   = B_ * T_ * M_ * 2;
constexpr int DO_LOGW  = DO_STD + B_ * T_ * M_;
constexpr int DO_CORR  = DO_LOGW + B_ * T_ * M_;
constexpr int DO_LAST  = DO_CORR + B_ * T_ * M_;
constexpr int DO_PHI   = DO_LAST + B_ * T_;
} // namespace

// ---------------------------------------------------------------------------
__device__ __forceinline__ float load_agent(const float* p) {
  return __hip_atomic_load(p, __ATOMIC_RELAXED, __HIP_MEMORY_SCOPE_AGENT);
}
__device__ __forceinline__ void store_agent(float* p, float v) {
  __hip_atomic_store(p, v, __ATOMIC_RELAXED, __HIP_MEMORY_SCOPE_AGENT);
}
__device__ __forceinline__ void store_agent_u32(unsigned* p, unsigned v) {
  __hip_atomic_store(p, v, __ATOMIC_RELAXED, __HIP_MEMORY_SCOPE_AGENT);
}
__device__ __forceinline__ unsigned long long load_agent_u64(const unsigned long long* p) {
  return __hip_atomic_load(p, __ATOMIC_RELAXED, __HIP_MEMORY_SCOPE_AGENT);
}
__device__ __forceinline__ ushort_t f2bf(float f) {
  union { float f; unsigned u; } x{f};
  unsigned r = x.u + 0x7FFFu + ((x.u >> 16) & 1u);
  return (ushort_t)(r >> 16);
}
__device__ __forceinline__ void split2(float f, ushort_t& h, ushort_t& l) {
  h = f2bf(f);
  union { unsigned u; float f; } c;
  c.u = ((unsigned)h) << 16;
  l = f2bf(f - c.f);
}
__device__ __forceinline__ float bfpair(ushort_t h, ushort_t l) {
  union { unsigned u; float f; } a, b;
  a.u = ((unsigned)h) << 16; b.u = ((unsigned)l) << 16;
  return a.f + b.f;
}
__device__ __forceinline__ float sigmoidf_(float x) {
  return 1.f / (1.f + __expf(-x));
}

// hierarchical fence-free grid barrier.
// bar[0]=gen, bar[64]=master, bar[128+64*g]=group counter (padded lines).
__device__ __forceinline__ void grid_barrier(unsigned* bar, int grp) {
  __builtin_amdgcn_s_waitcnt(0);
  __syncthreads();
  __atomic_signal_fence(__ATOMIC_SEQ_CST);
  if (threadIdx.x == 0) {
    unsigned g = __hip_atomic_load(bar, __ATOMIC_RELAXED, __HIP_MEMORY_SCOPE_AGENT);
    unsigned a = __hip_atomic_fetch_add(bar + 128 + 64 * grp, 1u,
                                        __ATOMIC_RELAXED, __HIP_MEMORY_SCOPE_AGENT);
    bool bump = false;
    if (a == (unsigned)(GRPSZ - 1)) {
      __hip_atomic_store(bar + 128 + 64 * grp, 0u, __ATOMIC_RELAXED,
                         __HIP_MEMORY_SCOPE_AGENT);
      __builtin_amdgcn_s_waitcnt(0);   // reset lands before master add
      unsigned b = __hip_atomic_fetch_add(bar + 64, 1u, __ATOMIC_RELAXED,
                                          __HIP_MEMORY_SCOPE_AGENT);
      if (b == (unsigned)(NGRP - 1)) {
        __hip_atomic_store(bar + 64, 0u, __ATOMIC_RELAXED, __HIP_MEMORY_SCOPE_AGENT);
        __builtin_amdgcn_s_waitcnt(0); // master reset lands before gen flip
        __hip_atomic_store(bar, g + 1u, __ATOMIC_RELAXED, __HIP_MEMORY_SCOPE_AGENT);
        bump = true;
      }
    }
    if (!bump) {
      while (__hip_atomic_load(bar, __ATOMIC_RELAXED, __HIP_MEMORY_SCOPE_AGENT) == g) {
        __builtin_amdgcn_s_sleep(1);
      }
    }
  }
  __atomic_signal_fence(__ATOMIC_SEQ_CST);
  __syncthreads();
}

// stage one packed-ring 16x400 region into LDS split arrays (koff = col base)
__device__ __forceinline__ void stage_ring16(const unsigned* __restrict__ src,
                                             ushort_t* __restrict__ BhB,
                                             ushort_t* __restrict__ BlB, int koff) {
  for (int pi = threadIdx.x; pi < 3200; pi += 256) {   // 6400 elems / 2
    int e = pi * 2;
    int b = e / 400, k = e - b * 400;
    unsigned long long v = load_agent_u64((const unsigned long long*)(src + e));
    unsigned p0 = (unsigned)v, p1 = (unsigned)(v >> 32);
    unsigned hp = (p0 >> 16) | (p1 & 0xFFFF0000u);
    unsigned lp = (p0 & 0xFFFFu) | (p1 << 16);
    *(unsigned*)(BhB + b * SBL + koff + k) = hp;
    *(unsigned*)(BlB + b * SBL + koff + k) = lp;
  }
}

// ---------------------------------------------------------------------------
__global__ __launch_bounds__(256)
void zero_ws(float* __restrict__ p) {
  size_t i = (size_t)blockIdx.x * 256 + threadIdx.x;
  if (i < ZERO_TOT) p[i] = 0.f;
}

__global__ void zero_feat_pads(ushort_t* __restrict__ fh, ushort_t* __restrict__ fl) {
  int idx = blockIdx.x * 256 + threadIdx.x;
  if (idx >= N_ * 48) return;
  int n = idx / 48, r = idx % 48;
  size_t o = (size_t)n * FEAT_LD + (r / 16) * SEG + 400 + (r % 16);
  fh[o] = 0; fl[o] = 0;
}

__global__ void split_wh_kernel(const float* __restrict__ Wh,
                                ushort_t* __restrict__ hi, ushort_t* __restrict__ lo) {
  int idx = blockIdx.x * 256 + threadIdx.x;
  if (idx >= 128 * FEAT_LD) return;
  int m = idx / FEAT_LD, k = idx % FEAT_LD;
  int seg = k / SEG, off = k % SEG;
  float v = (m < 121 && off < 400) ? Wh[(size_t)m * 1200 + seg * 400 + off] : 0.f;
  ushort_t h, l; split2(v, h, l);
  hi[idx] = h; lo[idx] = l;
}

__global__ __launch_bounds__(256)
void gemm_split_kernel(const ushort_t* __restrict__ Ahi, const ushort_t* __restrict__ Alo,
                       const ushort_t* __restrict__ Bhi, const ushort_t* __restrict__ Blo,
                       const float* __restrict__ bias, float* __restrict__ C,
                       int mtiles, int ntiles, int ktiles, int strideA, int strideB,
                       int Mvalid, int ldc) {
  int wave = blockIdx.x * 4 + (threadIdx.x >> 6);
  if (wave >= mtiles * ntiles) return;
  int mt = wave / ntiles, nt = wave % ntiles;
  int lane = threadIdx.x & 63, l15 = lane & 15, quad = lane >> 4;
  size_t aoff = (size_t)(mt * 16 + l15) * strideA + quad * 8;
  size_t boff = (size_t)(nt * 16 + l15) * strideB + quad * 8;
  f32x4 acc = {0.f, 0.f, 0.f, 0.f};
  for (int kt = 0; kt < ktiles; ++kt) {
    bf16x8 ah = *(const bf16x8*)(Ahi + aoff + kt * 32);
    bf16x8 al = *(const bf16x8*)(Alo + aoff + kt * 32);
    bf16x8 bh = *(const bf16x8*)(Bhi + boff + kt * 32);
    bf16x8 bl = *(const bf16x8*)(Blo + boff + kt * 32);
    acc = __builtin_amdgcn_mfma_f32_16x16x32_bf16(ah, bh, acc, 0, 0, 0);
    acc = __builtin_amdgcn_mfma_f32_16x16x32_bf16(ah, bl, acc, 0, 0, 0);
    acc = __builtin_amdgcn_mfma_f32_16x16x32_bf16(al, bh, acc, 0, 0, 0);
  }
  int n = nt * 16 + l15;
#pragma unroll
  for (int r = 0; r < 4; ++r) {
    int m = mt * 16 + quad * 4 + r;
    if (m < Mvalid) C[(size_t)n * ldc + m] = acc[r] + bias[m];
  }
}

// ---------------------------------------------------------------------------
// fused pipelined scan body (templated per layer)
template <int L>
__device__ __forceinline__ void scan_body(
    int slice, int bhalf, int grp,
    const float* __restrict__ x, const int* __restrict__ c,
    const float* __restrict__ Wih, const float* __restrict__ Whh,
    const float* __restrict__ bih, const float* __restrict__ bhh,
    const float* __restrict__ Ww, const float* __restrict__ bw,
    unsigned* __restrict__ ringS, const unsigned* __restrict__ ringP,
    const float* __restrict__ wring_c, float* __restrict__ wring_w,
    ushort_t* __restrict__ fh, ushort_t* __restrict__ fl,
    float* __restrict__ out_phi, unsigned* __restrict__ bar,
    ushort_t* Bh, ushort_t* Bl, float (*su)[65], float (*sp)[33],
    float (*skap)[10], unsigned char (*sc)[64]) {
  constexpr int KT = (L == 0) ? 15 : 27;
  constexpr int CONST_K = (L == 0) ? 463 : 863;
  constexpr int XOFF = (L == 0) ? 460 : 860;
  constexpr int WOFF = (L == 0) ? 400 : 800;
  constexpr int IW = (L == 0) ? 63 : 463;
  const int tid = threadIdx.x;
  const int waveid = tid >> 6, lane = tid & 63;
  const int l15 = lane & 15, quad = lane >> 4;
  const int rt = waveid;                 // rowtile 0..3
  const int m = l15;
  const int uu = m & 3, gate = m >> 2;   // 0=r 1=z 2=hn 3=inn
  const int J = slice * 16 + rt * 4 + uu;
  const int B0 = bhalf * 16;             // first global sample of this block

  // ---- main A-fragments (split bf16), in registers for all 512 steps ----
  bf16x8 afh[KT], afl[KT];
#pragma unroll
  for (int kt = 0; kt < KT; ++kt) {
    union { bf16x8 v; ushort_t s[8]; } uh, ul;
#pragma unroll
    for (int j = 0; j < 8; ++j) {
      int k = kt * 32 + quad * 8 + j;
      float v = 0.f;
      if (k < 400) {
        if (gate == 0)      v = Whh[(size_t)J * 400 + k];
        else if (gate == 1) v = Whh[(size_t)(400 + J) * 400 + k];
        else if (gate == 2) v = Whh[(size_t)(800 + J) * 400 + k];
      } else if (k < CONST_K) {
        int col;
        if (L == 0) col = (k < 460) ? 3 + (k - 400) : (k - 460);
        else        col = (k < 800) ? 3 + (k - 400)
                        : (k < 860) ? 403 + (k - 800) : (k - 860);
        if (gate == 0)      v = Wih[(size_t)J * IW + col];
        else if (gate == 1) v = Wih[(size_t)(400 + J) * IW + col];
        else if (gate == 3) v = Wih[(size_t)(800 + J) * IW + col];
      } else if (k == CONST_K) {
        if (gate == 0)      v = bih[J] + bhh[J];
        else if (gate == 1) v = bih[400 + J] + bhh[400 + J];
        else if (gate == 2) v = bhh[800 + J];
        else                v = bih[800 + J];
      }
      ushort_t h, l; split2(v, h, l);
      uh.s[j] = h; ul.s[j] = l;
    }
    afh[kt] = uh.v; afl[kt] = ul.v;
  }

  // ---- attention p-fragments (Ww rows, split), L0/L1: waves 0/1 own 16 rows
  bf16x8 apfh[14], apfl[14];
  if constexpr (L <= 1) {
    const int prow = (waveid < 2) ? (waveid * 16 + l15) : 32;
#pragma unroll
    for (int pk = 0; pk < 14; ++pk) {
      int kt = (pk < 13) ? ((L == 0) ? pk : 12 + pk) : ((L == 0) ? 14 : 26);
      union { bf16x8 v; ushort_t s[8]; } uh, ul;
#pragma unroll
      for (int j = 0; j < 8; ++j) {
        int k = kt * 32 + quad * 8 + j;
        int col = k - ((L == 0) ? 0 : 400);
        float v = 0.f;
        if (prow < 30) {
          if (col >= 0 && col < 400) v = Ww[prow * 400 + col];
          else if (k == CONST_K)     v = bw[prow];
        }
        ushort_t h, l; split2(v, h, l);
        uh.s[j] = h; ul.s[j] = l;
      }
      apfh[pk] = uh.v; apfl[pk] = ul.v;
    }
  }

  // ---- one-time LDS init ----
  for (int i = tid; i < 16 * SBL; i += 256) { Bh[i] = 0; Bl[i] = 0; }
  for (int i = tid; i < 160; i += 256) skap[i / 10][i % 10] = 0.f;
  if constexpr (L <= 1) {
    for (int i = tid; i < 16 * 64; i += 256)
      sc[i >> 6][i & 63] = (unsigned char)c[(B0 + (i >> 6)) * U_ + (i & 63)];
  }
  __syncthreads();
  if (tid < 16) Bh[tid * SBL + CONST_K] = 0x3F80;  // bf16(1.0); lo stays 0
  __syncthreads();

  // ---- pipelined time loop ----
  for (int iv = 0; iv < 514; ++iv) {
    int t = iv - L;
    if (t >= 0 && t < T_) {
      // -- staging: own h(t-1); L>=1 also h_prev(t); L2 also w(t); x(t) --
      stage_ring16(ringS + (size_t)((t + 3) & 3) * 12800 + B0 * 400, Bh, Bl, 0);
      if constexpr (L >= 1)
        stage_ring16(ringP + (size_t)(t & 3) * 12800 + B0 * 400, Bh, Bl, 400);
      if constexpr (L == 2) {
        const float* src = wring_c + (size_t)(t & 3) * 1920 + B0 * 60;
        for (int idx = tid; idx < 960; idx += 256) {
          int b = idx / 60, v = idx - b * 60;
          ushort_t h, l; split2(load_agent(src + idx), h, l);
          Bh[b * SBL + WOFF + v] = h; Bl[b * SBL + WOFF + v] = l;
        }
      }
      if (tid < 48) {
        int b = tid / 3, xc = tid - b * 3;
        ushort_t h, l;
        split2(x[((size_t)(B0 + b) * T_ + t) * 3 + xc], h, l);
        Bh[b * SBL + XOFF + xc] = h; Bl[b * SBL + XOFF + xc] = l;
      }
      __syncthreads();

      // -- attention (L0 computes w(t-1); L1 computes w(t)) --
      if constexpr (L <= 1) {
        const bool dow = (L == 1) || (t > 0);
        if (dow) {
          if (waveid < 2) {  // p-MFMA: rows waveid*16..+15 of 30, cols 16
            f32x4 acc = {0.f, 0.f, 0.f, 0.f};
            const int brow = l15 * SBL + quad * 8;
#pragma unroll
            for (int pk = 0; pk < 14; ++pk) {
              int kt = (pk < 13) ? ((L == 0) ? pk : 12 + pk) : ((L == 0) ? 14 : 26);
              bf16x8 bh8 = *(const bf16x8*)(Bh + brow + kt * 32);
              bf16x8 bl8 = *(const bf16x8*)(Bl + brow + kt * 32);
              acc = __builtin_amdgcn_mfma_f32_16x16x32_bf16(apfh[pk], bh8, acc, 0, 0, 0);
              acc = __builtin_amdgcn_mfma_f32_16x16x32_bf16(apfh[pk], bl8, acc, 0, 0, 0);
              acc = __builtin_amdgcn_mfma_f32_16x16x32_bf16(apfl[pk], bh8, acc, 0, 0, 0);
            }
#pragma unroll
            for (int r = 0; r < 4; ++r)
              sp[l15][waveid * 16 + quad * 4 + r] = acc[r];
          }
          __syncthreads();
          for (int idx = tid; idx < 480; idx += 256) {     // exp(p)
            int b = idx / 30, mm = idx - b * 30;
            sp[b][mm] = __expf(sp[b][mm]);
          }
          __syncthreads();
          for (int idx = tid; idx < 160; idx += 256) {     // kappa += dk
            int b = idx / 10, k2 = idx - b * 10;
            skap[b][k2] += sp[b][20 + k2];
          }
          __syncthreads();
          for (int idx = tid; idx < 1040; idx += 256) {    // phi
            int b = idx / 65, u = idx - b * 65;
            float s = 0.f;
#pragma unroll
            for (int k2 = 0; k2 < 10; ++k2) {
              float d = skap[b][k2] - (float)u;
              s = fmaf(sp[b][k2], __expf(-sp[b][10 + k2] * d * d), s);
            }
            su[b][u] = s;
          }
          __syncthreads();
          const int wt = (L == 0) ? t - 1 : t;
          for (int idx = tid; idx < 960; idx += 256) {     // w gather
            int b = idx / 60, v = idx - b * 60;
            float s = 0.f;
#pragma unroll 8
            for (int u = 0; u < U_; ++u)
              s += (sc[b][u] == v) ? su[b][u] : 0.f;
            ushort_t h, l; split2(s, h, l);
            Bh[b * SBL + WOFF + v] = h; Bl[b * SBL + WOFF + v] = l;
            if (L == 0 && slice == 0)
              store_agent(wring_w + (size_t)(wt & 3) * 1920 + B0 * 60 + idx, s);
          }
          if (L == 1 && t == T_ - 1 && slice == 0) {
            for (int idx = tid; idx < 1040; idx += 256)
              out_phi[(B0 + idx / 65) * 65 + (idx % 65)] = su[idx / 65][idx % 65];
          }
          __syncthreads();
        }
      }

      // -- main MFMA: rows = this wave's rowtile, cols = 16 samples --
      {
        f32x4 acc = {0.f, 0.f, 0.f, 0.f};
        const int brow = l15 * SBL + quad * 8;
#pragma unroll
        for (int kt = 0; kt < KT; ++kt) {
          bf16x8 bh8 = *(const bf16x8*)(Bh + brow + kt * 32);
          bf16x8 bl8 = *(const bf16x8*)(Bl + brow + kt * 32);
          acc = __builtin_amdgcn_mfma_f32_16x16x32_bf16(afh[kt], bh8, acc, 0, 0, 0);
          acc = __builtin_amdgcn_mfma_f32_16x16x32_bf16(afh[kt], bl8, acc, 0, 0, 0);
          acc = __builtin_amdgcn_mfma_f32_16x16x32_bf16(afl[kt], bh8, acc, 0, 0, 0);
        }
#pragma unroll
        for (int r = 0; r < 4; ++r)
          su[l15][rt * 16 + quad * 4 + r] = acc[r];   // su as sdots
      }
      __syncthreads();

      // -- combine: 256 threads = 16 samples x 16 units (unit fastest) --
      {
        int b = tid >> 4, u = tid & 15;
        int urt = u >> 2, u3 = u & 3;
        float rr = sigmoidf_(su[b][urt * 16 + 0 * 4 + u3]);
        float zz = sigmoidf_(su[b][urt * 16 + 1 * 4 + u3]);
        float hn = su[b][urt * 16 + 2 * 4 + u3];
        float inn = su[b][urt * 16 + 3 * 4 + u3];
        int Jc = slice * 16 + u;
        float hold = bfpair(Bh[b * SBL + Jc], Bl[b * SBL + Jc]);
        float hv = (1.f - zz) * tanhf(inn + rr * hn) + zz * hold;
        ushort_t hh, hl; split2(hv, hh, hl);
        store_agent_u32(ringS + (size_t)(t & 3) * 12800 + (B0 + b) * 400 + Jc,
                        ((unsigned)hh << 16) | (unsigned)hl);
        int n = (B0 + b) * T_ + t;
        size_t fo = (size_t)n * FEAT_LD + L * SEG + Jc;
        fh[fo] = hh; fl[fo] = hl;
      }
    }
    grid_barrier(bar, grp);
  }
}

__global__ __launch_bounds__(256, 1)
void fused_scan(const float* __restrict__ x, const int* __restrict__ c,
                const float* Wih0, const float* Whh0, const float* bih0, const float* bhh0,
                const float* Wih1, const float* Whh1, const float* bih1, const float* bhh1,
                const float* Wih2, const float* Whh2, const float* bih2, const float* bhh2,
                const float* __restrict__ Ww, const float* __restrict__ bw,
                unsigned* ring0, unsigned* ring1, unsigned* ring2, float* wring,
                ushort_t* __restrict__ fh, ushort_t* __restrict__ fl,
                float* __restrict__ out_phi, unsigned* __restrict__ bar) {
  __shared__ ushort_t Bh[16 * SBL];
  __shared__ ushort_t Bl[16 * SBL];
  __shared__ float su[16][65];     // sdots (64 rows) UNION sphi (65)
  __shared__ float sp[16][33];     // attention p (exp'ed); rows 30,31 unused
  __shared__ float skap[16][10];
  __shared__ unsigned char sc[16][64];

  const int bx = blockIdx.x;
  const int grpL = bx / 50, r = bx % 50;
  const int slice = r >> 1, bhalf = r & 1;
  const int grp = bx / GRPSZ;      // barrier group

  if (grpL == 0)
    scan_body<0>(slice, bhalf, grp, x, c, Wih0, Whh0, bih0, bhh0, Ww, bw,
                 ring0, nullptr, nullptr, wring, fh, fl, out_phi, bar,
                 Bh, Bl, su, sp, skap, sc);
  else if (grpL == 1)
    scan_body<1>(slice, bhalf, grp, x, c, Wih1, Whh1, bih1, bhh1, Ww, bw,
                 ring1, ring0, nullptr, nullptr, fh, fl, out_phi, bar,
                 Bh, Bl, su, sp, skap, sc);
  else
    scan_body<2>(slice, bhalf, grp, x, c, Wih2, Whh2, bih2, bhh2, Ww, bw,
                 ring2, ring1, wring, nullptr, fh, fl, out_phi, bar,
                 Bh, Bl, su, sp, skap, sc);
}

// ---------------------------------------------------------------------------
__global__ __launch_bounds__(256)
void post_kernel(const float* __restrict__ p, float* __restrict__ dout) {
  int n = blockIdx.x * 256 + threadIdx.x;
  if (n >= N_) return;
  const float* r = p + (size_t)n * 128;
  dout[DO_LAST + n] = r[0];
  float mx = -1e30f;
  for (int m = 0; m < M_; ++m) mx = fmaxf(mx, r[1 + m]);
  float s = 0.f;
  for (int m = 0; m < M_; ++m) s += __expf(r[1 + m] - mx);
  float lse = mx + logf(s);
  for (int m = 0; m < M_; ++m) dout[DO_LOGW + (size_t)n * M_ + m] = r[1 + m] - lse;
  for (int i = 0; i < 2 * M_; ++i) dout[DO_MEANS + (size_t)n * 2 * M_ + i] = r[21 + i];
  for (int m = 0; m < M_; ++m) dout[DO_STD + (size_t)n * M_ + m] = __expf(r[61 + m]);
  for (int m = 0; m < M_; ++m) dout[DO_CORR + (size_t)n * M_ + m] = tanhf(r[81 + m]);
}

// ---------------------------------------------------------------------------
extern "C" void kernel_launch(void* const* d_in, const int* in_sizes, int n_in,
                              void* d_out, int out_size, void* d_ws, size_t ws_size,
                              hipStream_t stream) {
  const float* x    = (const float*)d_in[0];
  const int*   c    = (const int*)d_in[1];
  const float* Wih0 = (const float*)d_in[2];
  const float* Whh0 = (const float*)d_in[3];
  const float* bih0 = (const float*)d_in[4];
  const float* bhh0 = (const float*)d_in[5];
  const float* Wih1 = (const float*)d_in[6];
  const float* Whh1 = (const float*)d_in[7];
  const float* bih1 = (const float*)d_in[8];
  const float* bhh1 = (const float*)d_in[9];
  const float* Wih2 = (const float*)d_in[10];
  const float* Whh2 = (const float*)d_in[11];
  const float* bih2 = (const float*)d_in[12];
  const float* bhh2 = (const float*)d_in[13];
  const float* Ww   = (const float*)d_in[14];
  const float* bw   = (const float*)d_in[15];
  const float* Wh   = (const float*)d_in[16];
  const float* bh   = (const float*)d_in[17];
  (void)in_sizes; (void)n_in; (void)out_size; (void)ws_size;

  float* ws = (float*)d_ws;
  unsigned* ring0 = (unsigned*)(ws + OFF_R0);
  unsigned* ring1 = (unsigned*)(ws + OFF_R1);
  unsigned* ring2 = (unsigned*)(ws + OFF_R2);
  float*    wring = ws + OFF_WRING;
  unsigned* bar   = (unsigned*)(ws + OFF_BAR);
  ushort_t* fh    = (ushort_t*)(ws + OFF_FEATH);
  ushort_t* fl    = (ushort_t*)(ws + OFF_FEATL);
  ushort_t* whh_  = (ushort_t*)(ws + OFF_WHH);
  ushort_t* whl_  = (ushort_t*)(ws + OFF_WHL);
  float*    pbuf  = ws + OFF_P;
  float*    dout  = (float*)d_out;

  const dim3 blk(256);

  zero_ws<<<dim3((int)((ZERO_TOT + 255) / 256)), blk, 0, stream>>>(ws);
  zero_feat_pads<<<dim3((N_ * 48) / 256), blk, 0, stream>>>(fh, fl);
  split_wh_kernel<<<dim3((128 * FEAT_LD) / 256), blk, 0, stream>>>(Wh, whh_, whl_);

  fused_scan<<<dim3(NBLK), blk, 0, stream>>>(
      x, c, Wih0, Whh0, bih0, bhh0, Wih1, Whh1, bih1, bhh1,
      Wih2, Whh2, bih2, bhh2, Ww, bw,
      ring0, ring1, ring2, wring, fh, fl, dout + DO_PHI, bar);

  gemm_split_kernel<<<dim3(8 * (N_ / 16) / 4), blk, 0, stream>>>(
      whh_, whl_, fh, fl, bh, pbuf, 8, N_ / 16, FEAT_LD / 32,
      FEAT_LD, FEAT_LD, 121, 128);
  post_kernel<<<dim3(N_ / 256), blk, 0, stream>>>(pbuf, dout);
}